// Round 16
// baseline (58.269 us; speedup 1.0000x reference)
//
#include <hip/hip_runtime.h>
#include <cmath>

#define B_SZ 2
#define LSEQ 2048
#define DDIM 1024
#define NDIM 16
#define HDIM 128
#define MROWS (B_SZ * LSEQ)    // 4096
#define NBIG (DDIM + 2 * NDIM) // 1056
#define NPAD 1088              // NBIG padded to 64

typedef __bf16 bf16x8 __attribute__((ext_vector_type(8)));
typedef __bf16 bf16x4 __attribute__((ext_vector_type(4)));
typedef float f32x4 __attribute__((ext_vector_type(4)));

// async global->LDS, 16B/lane; LDS dest = wave-uniform base + lane*16
__device__ __forceinline__ void glds16(const __bf16* g, __bf16* l) {
    __builtin_amdgcn_global_load_lds(
        (const __attribute__((address_space(1))) unsigned int*)g,
        (__attribute__((address_space(3))) unsigned int*)l, 16, 0, 0);
}

// pair-layout row slots
__device__ __forceinline__ int slot_xt(int d) { return (d >> 4) * 32 + (d & 15); }
__device__ __forceinline__ int slot_de(int d) { return (d >> 4) * 32 + 16 + (d & 15); }

// ---------------------------------------------------------------------------
// transpose helpers
// ---------------------------------------------------------------------------
__device__ __forceinline__ void tcast_tile(const float* __restrict__ in,
                                           __bf16* __restrict__ out, int K, int N,
                                           int bx, int by, float (*t)[33]) {
    int tx = threadIdx.x & 31, ty = threadIdx.x >> 5;
    int n0 = bx * 32, k0 = by * 32;
    #pragma unroll
    for (int i = 0; i < 4; ++i) {
        int k = k0 + ty + i * 8, n = n0 + tx;
        t[ty + i * 8][tx] = (k < K && n < N) ? in[(size_t)k * N + n] : 0.f;
    }
    __syncthreads();
    #pragma unroll
    for (int i = 0; i < 4; ++i) {
        int n = n0 + ty + i * 8, k = k0 + tx;
        if (n < N && k < K) out[(size_t)n * K + k] = (__bf16)t[tx][ty + i * 8];
    }
}

__device__ __forceinline__ void tcast_pair_tile(const float* __restrict__ in,
                                                __bf16* __restrict__ out,
                                                int bx, int by, float (*t)[33]) {
    int tx = threadIdx.x & 31, ty = threadIdx.x >> 5;
    int n0 = bx * 32, k0 = by * 32;
    #pragma unroll
    for (int i = 0; i < 4; ++i) {
        int k = k0 + ty + i * 8, n = n0 + tx;
        t[ty + i * 8][tx] = in[(size_t)k * 1024 + n];
    }
    __syncthreads();
    #pragma unroll
    for (int i = 0; i < 4; ++i) {
        int n = n0 + ty + i * 8, k = k0 + tx;
        out[(size_t)slot_xt(n) * 128 + k] = (__bf16)t[tx][ty + i * 8];
    }
}

// ---------------------------------------------------------------------------
// k1: only the WaT transposes (G1's B operand). 256 blocks.
// ---------------------------------------------------------------------------
__global__ __launch_bounds__(256) void pack_wat(const float* Wl1, const float* Wf1,
                                                __bf16* WaT) {
    __shared__ float t[32][33];
    const int b = blockIdx.x;
    if (b < 128) tcast_tile(Wl1, WaT, 1024, 128, b & 3, b >> 2, t);
    else {
        int i = b - 128;
        tcast_tile(Wf1, WaT + 128 * 1024, 1024, 128, i & 3, i >> 2, t);
    }
}

// ---------------------------------------------------------------------------
// Core BMxBN MFMA GEMM, templated BK/NBUF; takes tid so callers can run
// two independent 256-thread halves in a 512-thread block (equal barrier
// counts per half -> __syncthreads safe). XOR swizzle both sides.
// ACT: 1 relu(+prev), 2 fast-tanh, 4 split128-relu, 7 pair-scatter raw (Gpre)
// ---------------------------------------------------------------------------
template <int BM, int BN, int BK, int NBUF, int ACT, bool ADD_PREV, bool GUARDN, bool AF32>
__device__ __forceinline__ void gemm_core(
    const void* Av, int lda, const __bf16* __restrict__ Bt, int ldb, int Ntot,
    const float* __restrict__ bias, const __bf16* __restrict__ prev, int ldp,
    __bf16* __restrict__ C, int ldc, int K, int bm, int bn,
    __bf16* As, __bf16* Bs, int tid) {
    constexpr int WM = BM / 2, WN = BN / 2, FM = WM / 16, FN = WN / 16;
    constexpr int ASZ = BM * BK, BSZ = BN * BK;
    constexpr int CPR = BK / 8;
    constexpr int NH = BK / 32;
    const int lane = tid & 63, w = tid >> 6;
    const int wr = w >> 1, wc = w & 1;
    const int g = lane >> 4, lr = lane & 15;
    const __bf16* A16 = (const __bf16*)Av;
    const float* A32 = (const float*)Av;

    auto stage = [&](int buf, int k0) {
        #pragma unroll
        for (int i = 0; i < BM * BK / 2048; ++i) {
            int D = i * 256 + tid;
            int row = D / CPR, pos = D % CPR, c = pos ^ (row & 7);
            if constexpr (AF32) {
                const float* s = &A32[(size_t)(bm + row) * lda + k0 + c * 8];
                float4 v0 = *(const float4*)s;
                float4 v1 = *(const float4*)(s + 4);
                bf16x8 pk = {(__bf16)v0.x, (__bf16)v0.y, (__bf16)v0.z, (__bf16)v0.w,
                             (__bf16)v1.x, (__bf16)v1.y, (__bf16)v1.z, (__bf16)v1.w};
                *(bf16x8*)&As[buf * ASZ + row * BK + pos * 8] = pk;
            } else {
                glds16(&A16[(size_t)(bm + row) * lda + k0 + c * 8],
                       &As[buf * ASZ + (i * 256 + w * 64) * 8]);
            }
        }
        #pragma unroll
        for (int i = 0; i < BN * BK / 2048; ++i) {
            int D = i * 256 + tid;
            int row = D / CPR, pos = D % CPR, c = pos ^ (row & 7);
            glds16(&Bt[(size_t)(bn + row) * ldb + k0 + c * 8],
                   &Bs[buf * BSZ + (i * 256 + w * 64) * 8]);
        }
    };

    f32x4 acc[FM][FN] = {};
    const int x7 = lr & 7;
    int ca[NH];
    #pragma unroll
    for (int h = 0; h < NH; ++h) ca[h] = ((h * 4 + g) ^ x7) * 8;
    const int arow0 = wr * WM + lr;
    const int brow0 = wc * WN + lr;

    const int nt = K / BK;
    stage(0, 0);
    __syncthreads();
    for (int t = 0; t < nt; ++t) {
        if (NBUF == 2 && t + 1 < nt) stage((t + 1) & 1, (t + 1) * BK);
        const __bf16* Ab = &As[(NBUF == 2 ? (t & 1) : 0) * ASZ];
        const __bf16* Bb = &Bs[(NBUF == 2 ? (t & 1) : 0) * BSZ];
        bf16x8 af[FM][NH], bfr[FN][NH];
        #pragma unroll
        for (int m = 0; m < FM; ++m)
            #pragma unroll
            for (int h = 0; h < NH; ++h)
                af[m][h] = *(const bf16x8*)&Ab[(arow0 + m * 16) * BK + ca[h]];
        #pragma unroll
        for (int n = 0; n < FN; ++n)
            #pragma unroll
            for (int h = 0; h < NH; ++h)
                bfr[n][h] = *(const bf16x8*)&Bb[(brow0 + n * 16) * BK + ca[h]];
        #pragma unroll
        for (int h = 0; h < NH; ++h)
            #pragma unroll
            for (int m = 0; m < FM; ++m)
                #pragma unroll
                for (int n = 0; n < FN; ++n)
                    acc[m][n] = __builtin_amdgcn_mfma_f32_16x16x32_bf16(
                        af[m][h], bfr[n][h], acc[m][n], 0, 0, 0);
        __syncthreads();
    }

    #pragma unroll
    for (int m = 0; m < FM; ++m) {
        #pragma unroll
        for (int n = 0; n < FN; ++n) {
            #pragma unroll
            for (int r = 0; r < 4; ++r) {
                int grow = bm + wr * WM + m * 16 + g * 4 + r;
                int gcol = bn + wc * WN + n * 16 + lr;
                if (!GUARDN || gcol < Ntot) {
                    float v = acc[m][n][r];
                    int orow = grow;
                    if (ACT == 1) {
                        v += bias[gcol];
                        if (ADD_PREV) v += (float)prev[(size_t)grow * ldp + gcol];
                        v = fmaxf(v, 0.f);
                    } else if (ACT == 2) {
                        v += bias[gcol];
                        float e = __expf(2.f * v);
                        v = 1.f - 2.f * __builtin_amdgcn_rcpf(e + 1.f);
                    } else if (ACT == 4) {
                        if (gcol < HDIM) v = fmaxf(v + bias[gcol], 0.f);
                    } else if (ACT == 7) { // Gpre pair-scatter, raw
                        orow = (grow < 1024) ? slot_de(grow) : 2048 + (grow - 1024);
                    }
                    C[(size_t)orow * ldc + gcol] = (__bf16)v;
                }
            }
        }
    }
}

// ---------------------------------------------------------------------------
// k2: G1 (512 blk, needs only WaT) || rest-of-pack (1541 blk, no deps).
// ---------------------------------------------------------------------------
__global__ __launch_bounds__(256) void stage1_k(
    const float* __restrict__ x, const __bf16* __restrict__ WaT,
    const float* W1, const float* W2, const float* W3, const float* Wl2,
    const float* Wf1, const float* Wf2, const float* bf2, const float* h0,
    const float* __restrict__ bl1,
    __bf16* __restrict__ tmp12, __bf16* WbigT, __bf16* Wf1bT, __bf16* Wl2T,
    __bf16* WpairT, __bf16* Wf2c, float* bias_pair, unsigned* h0mask) {
    __shared__ __bf16 As[8192];
    __shared__ __bf16 Bs[16384];
    __shared__ float t[32][33];
    const int b = blockIdx.x;
    const int tid = threadIdx.x;
    if (b < 512) {
        // G1: tmp12 = [relu(x@Wl1+bl1) | x@Wf1_top]  M=4096 N=256 K=1024
        const int aid = (b & 7) * 64 + (b >> 3);
        const int bn = (aid & 3) * 64, bm = (aid >> 2) * 32;
        gemm_core<32, 64, 128, 2, 4, false, false, true>(
            x, DDIM, WaT, 1024, 256, bl1, nullptr, 0, tmp12, 256, 1024, bm, bn,
            As, Bs, tid);
    } else if (b < 1536) {                // W1 -> WbigT
        int i = b - 512; tcast_tile(W1, WbigT, 1024, 1024, i & 31, i >> 5, t);
    } else if (b < 1664) {                // Wf1 bottom -> Wf1bT
        int i = b - 1536;
        tcast_tile(Wf1 + (size_t)1024 * 128, Wf1bT, 1024, 128, i & 3, i >> 2, t);
    } else if (b < 1792) {                // Wl2 -> Wl2T
        int i = b - 1664; tcast_tile(Wl2, Wl2T, 128, 1024, i & 31, i >> 5, t);
    } else if (b < 1920) {                // Wf2 -> WpairT xt slots
        int i = b - 1792; tcast_pair_tile(Wf2, WpairT, i & 31, i >> 5, t);
    } else if (b < 1952) {                // W2 -> WbigT[1024..]
        int i = b - 1920; tcast_tile(W2, WbigT + (size_t)1024 * 1024, 1024, 16, 0, i, t);
    } else if (b < 1984) {                // W3 -> WbigT[1040..]
        int i = b - 1952; tcast_tile(W3, WbigT + (size_t)1040 * 1024, 1024, 16, 0, i, t);
    } else if (b < 1988) {                // xt bias scatter
        int i = (b - 1984) * 256 + tid;
        bias_pair[slot_xt(i)] = bf2[i];
    } else if (b < 2020) {                // zero WbigT pad rows
        int i = (b - 1988) * 256 + tid;
        #pragma unroll
        for (int r = 0; r < 4; ++r) {
            int e = i + r * 8192;
            if (e < 32 * 1024) WbigT[(size_t)1056 * 1024 + e] = (__bf16)0.f;
        }
    } else if (b < 2052) {                // Wf2 -> Wf2c row-major bf16
        int id = (b - 2020) * 256 + tid;
        #pragma unroll
        for (int j = 0; j < 4; ++j) {
            int e = id + j * 8192;
            float4 v = ((const float4*)Wf2)[e];
            bf16x4 o2 = {(__bf16)v.x, (__bf16)v.y, (__bf16)v.z, (__bf16)v.w};
            ((bf16x4*)Wf2c)[e] = o2;
        }
    } else {                              // h0 nonzero bitmask
        __shared__ unsigned sm[32];
        if (tid < 32) sm[tid] = 0u;
        __syncthreads();
        unsigned nib = 0;
        #pragma unroll
        for (int j = 0; j < 4; ++j) {
            int d = tid * 4 + j;
            const uint4* hu = (const uint4*)(h0 + d * NDIM);
            uint4 a0 = hu[0], a1 = hu[1], a2 = hu[2], a3 = hu[3];
            unsigned nz = a0.x | a0.y | a0.z | a0.w | a1.x | a1.y | a1.z | a1.w |
                          a2.x | a2.y | a2.z | a2.w | a3.x | a3.y | a3.z | a3.w;
            if (nz) nib |= (1u << j);
        }
        if (nib) atomicOr(&sm[(tid * 4) >> 5], nib << ((tid * 4) & 31));
        __syncthreads();
        if (tid < 32) h0mask[tid] = sm[tid];
    }
}

// ---------------------------------------------------------------------------
// k3 (512 thr): [0,256) g23 (fused G2+G3); [256,290) Gpre as two 256-thread
// halves; [290,422) bias fold (8 waves). Gpre/bias hide under g23.
// ---------------------------------------------------------------------------
__global__ __launch_bounds__(512) void stage3_k(
    const __bf16* __restrict__ tmp12, const __bf16* __restrict__ Wl2T,
    const __bf16* __restrict__ Wf1bT, const __bf16* __restrict__ WbigT,
    const __bf16* __restrict__ Wf2c,
    const float* __restrict__ bl2, const float* __restrict__ bf1,
    const float* __restrict__ bf2, const float* __restrict__ b1,
    const float* __restrict__ b2, const float* __restrict__ b3,
    __bf16* __restrict__ tmp2, __bf16* __restrict__ WpairT,
    float* __restrict__ bias_pair) {
    __shared__ __bf16 smem[69632]; // 139 KB
    const int b = blockIdx.x;
    const int tid = threadIdx.x;
    if (b < 256) {
        // ---- g23: fused G2+G3 over 16 rows ----
        __bf16* T1 = smem;               // 2048
        __bf16* LS = smem + 2048;        // 2048
        __bf16* B1 = smem + 4096;        // 2 x 16384
        __bf16* B2 = smem + 36864;       // 2 x 16384
        const int lane = tid & 63, w = tid >> 6;
        const int g = lane >> 4, lr = lane & 15;
        const int x7 = lr & 7;
        const int bm = b * 16;

        if (tid < 256) {
            int row = tid >> 4, pos = tid & 15, c = pos ^ (row & 7);
            glds16(&tmp12[(size_t)(bm + row) * 256 + c * 8], &T1[w * 512]);
        }
        auto stageB = [&](int buf, int kc) {
            #pragma unroll
            for (int i = 0; i < 4; ++i) {
                int D = i * 512 + tid;
                int row = D >> 4, pos = D & 15, c = pos ^ (row & 7);
                glds16(&Wl2T[(size_t)(kc + row) * 128 + c * 8],
                       &B1[buf * 16384 + (i * 512 + w * 64) * 8]);
                glds16(&Wf1bT[(size_t)row * 1024 + kc + c * 8],
                       &B2[buf * 16384 + (i * 512 + w * 64) * 8]);
            }
        };

        int ca[4];
        #pragma unroll
        for (int h = 0; h < 4; ++h) ca[h] = ((h * 4 + g) ^ x7) * 8;
        const int col = w * 16 + lr;
        const int brow = col * 128;

        stageB(0, 0);
        __syncthreads();
        bf16x8 a1[4];
        #pragma unroll
        for (int h = 0; h < 4; ++h) a1[h] = *(const bf16x8*)&T1[lr * 128 + ca[h]];

        f32x4 acc2 = {};
        for (int t = 0; t < 8; ++t) {
            if (t + 1 < 8) stageB((t + 1) & 1, (t + 1) * 128);
            const __bf16* b1b = &B1[(t & 1) * 16384];
            const __bf16* b2b = &B2[(t & 1) * 16384];
            f32x4 acc1 = {};
            #pragma unroll
            for (int h = 0; h < 4; ++h) {
                bf16x8 bf = *(const bf16x8*)&b1b[brow + ca[h]];
                acc1 = __builtin_amdgcn_mfma_f32_16x16x32_bf16(a1[h], bf, acc1, 0, 0, 0);
            }
            const float bl = bl2[t * 128 + col];
            const int chunk = col >> 3, cin = col & 7;
            #pragma unroll
            for (int r = 0; r < 4; ++r) {
                float v = acc1[r] + bl;
                float e = __expf(2.f * v);
                v = 1.f - 2.f * __builtin_amdgcn_rcpf(e + 1.f);  // tanh
                int row = g * 4 + r;
                LS[row * 128 + ((chunk ^ (row & 7)) << 3) + cin] = (__bf16)v;
            }
            __syncthreads();
            #pragma unroll
            for (int h = 0; h < 4; ++h) {
                bf16x8 a2 = *(const bf16x8*)&LS[lr * 128 + ca[h]];
                bf16x8 bf = *(const bf16x8*)&b2b[brow + ca[h]];
                acc2 = __builtin_amdgcn_mfma_f32_16x16x32_bf16(a2, bf, acc2, 0, 0, 0);
            }
            __syncthreads();
        }

        const float bfv = bf1[col];
        #pragma unroll
        for (int r = 0; r < 4; ++r) {
            const int row = g * 4 + r;
            float v = acc2[r] + bfv + (float)tmp12[(size_t)(bm + row) * 256 + 128 + col];
            v = fmaxf(v, 0.f);
            tmp2[(size_t)(bm + row) * 128 + col] = (__bf16)v;
        }
    } else if (b < 290) {
        // ---- Gpre: 34 blocks x two 256-thread halves ----
        const int half = tid >> 8, tidh = tid & 255;
        const int aid = (b - 256) * 2 + half;          // 0..67
        const int bm = (aid >> 1) * 32, bn = (aid & 1) * 64;
        __bf16* Ah = smem + half * 24576;              // 8192 A + 16384 B
        __bf16* Bh = Ah + 8192;
        gemm_core<32, 64, 128, 2, 7, false, false, false>(
            WbigT, 1024, Wf2c, 1024, 128, nullptr, nullptr, 0,
            WpairT, 128, 1024, bm, bn, Ah, Bh, tidh);
    } else {
        // ---- bias fold: 132 blocks x 8 waves, n = base + wave ----
        const int n = (b - 290) * 8 + (tid >> 6);
        const int lane = tid & 63;
        const __bf16* wr = WbigT + (size_t)n * 1024 + lane * 16;
        float s = 0.f;
        #pragma unroll
        for (int i = 0; i < 2; ++i) {
            bf16x8 wv = *(const bf16x8*)&wr[i * 8];
            float4 f0 = *(const float4*)&bf2[lane * 16 + i * 8];
            float4 f1 = *(const float4*)&bf2[lane * 16 + i * 8 + 4];
            s += (float)wv[0] * f0.x + (float)wv[1] * f0.y + (float)wv[2] * f0.z +
                 (float)wv[3] * f0.w + (float)wv[4] * f1.x + (float)wv[5] * f1.y +
                 (float)wv[6] * f1.z + (float)wv[7] * f1.w;
        }
        #pragma unroll
        for (int off = 32; off; off >>= 1) s += __shfl_down(s, off);
        if (lane == 0) {
            float base = (n < DDIM) ? b1[n]
                       : (n < DDIM + NDIM) ? b2[n - DDIM] : b3[n - DDIM - NDIM];
            int sl = (n < DDIM) ? slot_de(n) : 2048 + (n - DDIM);
            bias_pair[sl] = base + s;
        }
    }
}

// ---------------------------------------------------------------------------
// mm_pairs: [xt|de] pair GEMM + in-kernel BC (Bm/Cm/cb) + final epilogue.
// M=4096 N=2048 K=128. BM=128 BN=64, 1024 blocks, LDS 48 KB. (unchanged)
// ---------------------------------------------------------------------------
__global__ __launch_bounds__(256) void mm_pairs(
    const __bf16* __restrict__ tmp2, const __bf16* __restrict__ WpairT,
    const float* __restrict__ bias_pair,
    const float* __restrict__ Amat, const float* __restrict__ h0,
    const unsigned* __restrict__ h0mask,
    float* __restrict__ out, float* __restrict__ last_h) {
    constexpr int ASZ = 128 * 64, BSZ = 64 * 64;
    __shared__ __bf16 As[2 * ASZ];
    __shared__ __bf16 Bs[2 * BSZ];
    const int NB = gridDim.x; // 1024
    const int aid = (blockIdx.x & 7) * (NB >> 3) + (blockIdx.x >> 3);
    const int bn = (aid & 31) * 64, bm = (aid >> 5) * 128;
    const int tid = threadIdx.x;
    const int lane = tid & 63, w = tid >> 6;
    const int wr = w >> 1, wc = w & 1;
    const int g = lane >> 4, lr = lane & 15;

    auto stage = [&](int buf, int k0) {
        #pragma unroll
        for (int i = 0; i < 4; ++i) {
            int D = i * 256 + tid;
            int row = D >> 3, pos = D & 7, c = pos ^ (row & 7);
            glds16(&tmp2[(size_t)(bm + row) * 128 + k0 + c * 8],
                   &As[buf * ASZ + (i * 256 + w * 64) * 8]);
        }
        #pragma unroll
        for (int i = 0; i < 2; ++i) {
            int D = i * 256 + tid;
            int row = D >> 3, pos = D & 7, c = pos ^ (row & 7);
            glds16(&WpairT[(size_t)(bn + row) * 128 + k0 + c * 8],
                   &Bs[buf * BSZ + (i * 256 + w * 64) * 8]);
        }
    };

    f32x4 acc[4][2] = {};
    const int x7 = lr & 7;
    const int ca[2] = {(g ^ x7) * 8, ((4 + g) ^ x7) * 8};
    const int arow0 = wr * 64 + lr, brow0 = wc * 32 + lr;
    stage(0, 0);
    __syncthreads();
    #pragma unroll
    for (int t = 0; t < 2; ++t) {
        if (t == 0) stage(1, 64);
        const __bf16* Ab = &As[t * ASZ];
        const __bf16* Bb = &Bs[t * BSZ];
        bf16x8 af[4][2], bfr[2][2];
        #pragma unroll
        for (int m = 0; m < 4; ++m)
            #pragma unroll
            for (int h = 0; h < 2; ++h)
                af[m][h] = *(const bf16x8*)&Ab[(arow0 + m * 16) * 64 + ca[h]];
        #pragma unroll
        for (int n = 0; n < 2; ++n)
            #pragma unroll
            for (int h = 0; h < 2; ++h)
                bfr[n][h] = *(const bf16x8*)&Bb[(brow0 + n * 16) * 64 + ca[h]];
        #pragma unroll
        for (int h = 0; h < 2; ++h)
            #pragma unroll
            for (int m = 0; m < 4; ++m)
                #pragma unroll
                for (int n = 0; n < 2; ++n)
                    acc[m][n] = __builtin_amdgcn_mfma_f32_16x16x32_bf16(
                        af[m][h], bfr[n][h], acc[m][n], 0, 0, 0);
        __syncthreads();
    }

    // in-kernel BC
    {
        int row = tid >> 3, pos = tid & 7, c = pos ^ (row & 7);
        #pragma unroll
        for (int t2 = 0; t2 < 2; ++t2)
            glds16(&WpairT[(size_t)(2048 + row) * 128 + t2 * 64 + c * 8],
                   &Bs[t2 * 2048 + w * 512]);
    }
    __syncthreads();
    f32x4 accB[2] = {}, accC[2] = {};
    #pragma unroll
    for (int t2 = 0; t2 < 2; ++t2) {
        const __bf16* Ab = &As[t2 * ASZ];
        #pragma unroll
        for (int h = 0; h < 2; ++h) {
            bf16x8 bB = *(const bf16x8*)&Bs[t2 * 2048 + lr * 64 + ca[h]];
            bf16x8 bC = *(const bf16x8*)&Bs[t2 * 2048 + (16 + lr) * 64 + ca[h]];
            #pragma unroll
            for (int m2 = 0; m2 < 2; ++m2) {
                bf16x8 a2 = *(const bf16x8*)&Ab[(w * 32 + m2 * 16 + lr) * 64 + ca[h]];
                accB[m2] = __builtin_amdgcn_mfma_f32_16x16x32_bf16(a2, bB, accB[m2], 0, 0, 0);
                accC[m2] = __builtin_amdgcn_mfma_f32_16x16x32_bf16(a2, bC, accC[m2], 0, 0, 0);
            }
        }
    }
    __syncthreads();
    float* sCB = (float*)As;
    __bf16* sBC = &Bs[BSZ];
    const float bB_ = bias_pair[2048 + lr], bC_ = bias_pair[2064 + lr];
    #pragma unroll
    for (int m2 = 0; m2 < 2; ++m2) {
        #pragma unroll
        for (int r = 0; r < 4; ++r) {
            int lrow = w * 32 + m2 * 16 + g * 4 + r;
            float vB = accB[m2][r] + bB_;
            float vC = accC[m2][r] + bC_;
            sBC[lrow * 32 + lr] = (__bf16)vB;
            sBC[lrow * 32 + 16 + lr] = (__bf16)vC;
            float p = vB * vC;
            #pragma unroll
            for (int m3 = 1; m3 < 16; m3 <<= 1) p += __shfl_xor(p, m3);
            if (lr == 0) sCB[lrow] = p;
        }
    }
    __syncthreads();

    const int d = ((bn + wc * 32) >> 1) + lr;
    const float bx_ = bias_pair[bn + wc * 32 + lr];
    const float bd_ = bias_pair[bn + wc * 32 + 16 + lr];
    const bool msk = (h0mask[d >> 5] >> (d & 31)) & 1u;
    #pragma unroll
    for (int m = 0; m < 4; ++m) {
        #pragma unroll
        for (int r = 0; r < 4; ++r) {
            const int lrow = wr * 64 + m * 16 + g * 4 + r;
            const int row = bm + lrow;
            const float xt = acc[m][0][r] + bx_;
            const float dr = acc[m][1][r] + bd_;
            const float e = __expf(-fabsf(dr));
            const float de = fmaxf(dr, 0.f) + __logf(1.f + e);
            const float xd = xt * de;
            float res = xd * sCB[lrow];
            const bool is_last = (row & (LSEQ - 1)) == (LSEQ - 1);
            if (msk) {
                float s = 0.f;
                #pragma unroll
                for (int n = 0; n < NDIM; ++n) {
                    float z = de * Amat[d * NDIM + n];
                    float c2 = (z > 0.f) ? z : __expf(z) - 1.f;
                    float da = __expf(-c2);
                    float h0v = h0[d * NDIM + n];
                    s += (float)sBC[lrow * 32 + 16 + n] * da * h0v;
                    if (is_last)
                        last_h[(((size_t)(row >> 11)) * DDIM + d) * NDIM + n] =
                            da * h0v + xd * (float)sBC[lrow * 32 + n];
                }
                res += s;
            } else if (is_last) {
                #pragma unroll
                for (int n = 0; n < NDIM; ++n)
                    last_h[(((size_t)(row >> 11)) * DDIM + d) * NDIM + n] =
                        xd * (float)sBC[lrow * 32 + n];
            }
            out[(size_t)row * DDIM + d] = res;
        }
    }
}

extern "C" void kernel_launch(void* const* d_in, const int* in_sizes, int n_in,
                              void* d_out, int out_size, void* d_ws, size_t ws_size,
                              hipStream_t stream) {
    const float* x   = (const float*)d_in[0];
    const float* W1  = (const float*)d_in[1];
    const float* b1  = (const float*)d_in[2];
    const float* W2  = (const float*)d_in[3];
    const float* b2  = (const float*)d_in[4];
    const float* W3  = (const float*)d_in[5];
    const float* b3  = (const float*)d_in[6];
    const float* Wl1 = (const float*)d_in[7];
    const float* bl1 = (const float*)d_in[8];
    const float* Wl2 = (const float*)d_in[9];
    const float* bl2 = (const float*)d_in[10];
    const float* Wf1 = (const float*)d_in[11];
    const float* bf1 = (const float*)d_in[12];
    const float* Wf2 = (const float*)d_in[13];
    const float* bf2 = (const float*)d_in[14];
    const float* h0  = (const float*)d_in[15];
    const float* Amat= (const float*)d_in[16];

    float* out    = (float*)d_out;
    float* last_h = (float*)d_out + (size_t)MROWS * DDIM;

    __bf16* wsb = (__bf16*)d_ws;
    size_t o = 0;
    auto alloc = [&](size_t n) { __bf16* p = wsb + o; o += n; return p; };
    __bf16* WaT    = alloc(256 * 1024);             // [Wl1 | Wf1_top]^T
    __bf16* Wf1bT  = alloc(128 * 1024);
    __bf16* Wl2T   = alloc(1024 * 128);
    __bf16* WbigT  = alloc((size_t)NPAD * 1024);    // [W1 | W2 | W3 | pad]^T
    __bf16* WpairT = alloc(2112 * 128);             // pairs 0..2047, BC 2048..2079
    __bf16* Wf2c   = alloc(128 * 1024);             // Wf2 bf16 row-major
    __bf16* tmp12  = alloc((size_t)MROWS * 256);    // [relu(x@Wl1+bl1) | x@Wf1_top]
    __bf16* tmp2   = alloc((size_t)MROWS * HDIM);
    float*  bias_pair = (float*)(wsb + o); o += 2 * 2112;
    unsigned* h0mask = (unsigned*)(wsb + o);

    // k1: WaT only (G1's B operand)
    pack_wat<<<dim3(256), 256, 0, stream>>>(Wl1, Wf1, WaT);
    // k2: G1 (512) || rest-of-pack (1541)
    stage1_k<<<dim3(2053), 256, 0, stream>>>(x, WaT, W1, W2, W3, Wl2, Wf1, Wf2,
                                             bf2, h0, bl1, tmp12, WbigT, Wf1bT,
                                             Wl2T, WpairT, Wf2c, bias_pair, h0mask);
    // k3: g23 (256) || Gpre (34x2 halves) || bias fold (132)
    stage3_k<<<dim3(422), 512, 0, stream>>>(tmp12, Wl2T, Wf1bT, WbigT, Wf2c,
                                            bl2, bf1, bf2, b1, b2, b3,
                                            tmp2, WpairT, bias_pair);
    // k4: mm_pairs -> out, last_h
    mm_pairs<<<dim3(32 * 32), 256, 0, stream>>>(tmp2, WpairT, bias_pair,
                                                Amat, h0, h0mask, out, last_h);
}

// Round 17
// 51.715 us; speedup vs baseline: 1.1267x; 1.1267x over previous
//
#include <hip/hip_runtime.h>
#include <cmath>

#define B_SZ 2
#define LSEQ 2048
#define DDIM 1024
#define NDIM 16
#define HDIM 128
#define MROWS (B_SZ * LSEQ)    // 4096
#define NBIG (DDIM + 2 * NDIM) // 1056
#define NPAD 1088              // NBIG padded to 64

typedef __bf16 bf16x8 __attribute__((ext_vector_type(8)));
typedef __bf16 bf16x4 __attribute__((ext_vector_type(4)));
typedef float f32x4 __attribute__((ext_vector_type(4)));

// async global->LDS, 16B/lane; LDS dest = wave-uniform base + lane*16
__device__ __forceinline__ void glds16(const __bf16* g, __bf16* l) {
    __builtin_amdgcn_global_load_lds(
        (const __attribute__((address_space(1))) unsigned int*)g,
        (__attribute__((address_space(3))) unsigned int*)l, 16, 0, 0);
}

// pair-layout row slots
__device__ __forceinline__ int slot_xt(int d) { return (d >> 4) * 32 + (d & 15); }
__device__ __forceinline__ int slot_de(int d) { return (d >> 4) * 32 + 16 + (d & 15); }

// ---------------------------------------------------------------------------
// Preprocessing (flat 1-D grid, 1797 blocks).
// ---------------------------------------------------------------------------
__device__ __forceinline__ void tcast_tile(const float* __restrict__ in,
                                           __bf16* __restrict__ out, int K, int N,
                                           int bx, int by, float (*t)[33]) {
    int tx = threadIdx.x & 31, ty = threadIdx.x >> 5;
    int n0 = bx * 32, k0 = by * 32;
    #pragma unroll
    for (int i = 0; i < 4; ++i) {
        int k = k0 + ty + i * 8, n = n0 + tx;
        t[ty + i * 8][tx] = (k < K && n < N) ? in[(size_t)k * N + n] : 0.f;
    }
    __syncthreads();
    #pragma unroll
    for (int i = 0; i < 4; ++i) {
        int n = n0 + ty + i * 8, k = k0 + tx;
        if (n < N && k < K) out[(size_t)n * K + k] = (__bf16)t[tx][ty + i * 8];
    }
}

// Wf2 [128][1024] -> WpairT xt slots (row slot_xt(n), ld 128)
__device__ __forceinline__ void tcast_pair_tile(const float* __restrict__ in,
                                                __bf16* __restrict__ out,
                                                int bx, int by, float (*t)[33]) {
    int tx = threadIdx.x & 31, ty = threadIdx.x >> 5;
    int n0 = bx * 32, k0 = by * 32;
    #pragma unroll
    for (int i = 0; i < 4; ++i) {
        int k = k0 + ty + i * 8, n = n0 + tx;
        t[ty + i * 8][tx] = in[(size_t)k * 1024 + n];
    }
    __syncthreads();
    #pragma unroll
    for (int i = 0; i < 4; ++i) {
        int n = n0 + ty + i * 8, k = k0 + tx;
        out[(size_t)slot_xt(n) * 128 + k] = (__bf16)t[tx][ty + i * 8];
    }
}

__global__ __launch_bounds__(256) void pack_all(
    const float* W1, const float* W2, const float* W3, const float* Wl1,
    const float* Wl2, const float* Wf1, const float* Wf2,
    const float* bf2, const float* h0,
    __bf16* WbigT, __bf16* WaT, __bf16* Wf1bT, __bf16* Wl2T, __bf16* WpairT,
    __bf16* Wf2c, float* bias_pair, unsigned* h0mask) {
    __shared__ float t[32][33];
    const int b = blockIdx.x;
    const int tid = threadIdx.x;
    if (b < 1024) {                       // W1 -> WbigT
        tcast_tile(W1, WbigT, 1024, 1024, b & 31, b >> 5, t);
    } else if (b < 1152) {                // Wl1 -> WaT
        int i = b - 1024; tcast_tile(Wl1, WaT, 1024, 128, i & 3, i >> 2, t);
    } else if (b < 1280) {                // Wf1 top -> WaT[128k..]
        int i = b - 1152; tcast_tile(Wf1, WaT + 128 * 1024, 1024, 128, i & 3, i >> 2, t);
    } else if (b < 1408) {                // Wf1 bottom -> Wf1bT
        int i = b - 1280;
        tcast_tile(Wf1 + (size_t)1024 * 128, Wf1bT, 1024, 128, i & 3, i >> 2, t);
    } else if (b < 1536) {                // Wl2 -> Wl2T
        int i = b - 1408; tcast_tile(Wl2, Wl2T, 128, 1024, i & 31, i >> 5, t);
    } else if (b < 1664) {                // Wf2 -> WpairT xt slots
        int i = b - 1536; tcast_pair_tile(Wf2, WpairT, i & 31, i >> 5, t);
    } else if (b < 1696) {                // W2 -> WbigT[1024..]
        int i = b - 1664; tcast_tile(W2, WbigT + (size_t)1024 * 1024, 1024, 16, 0, i, t);
    } else if (b < 1728) {                // W3 -> WbigT[1040..]
        int i = b - 1696; tcast_tile(W3, WbigT + (size_t)1040 * 1024, 1024, 16, 0, i, t);
    } else if (b < 1732) {                // xt bias scatter
        int i = (b - 1728) * 256 + tid;
        bias_pair[slot_xt(i)] = bf2[i];
    } else if (b < 1764) {                // zero WbigT pad rows
        int i = (b - 1732) * 256 + tid;
        #pragma unroll
        for (int r = 0; r < 4; ++r) {
            int e = i + r * 8192;
            if (e < 32 * 1024) WbigT[(size_t)1056 * 1024 + e] = (__bf16)0.f;
        }
    } else if (b < 1796) {                // Wf2 -> Wf2c row-major bf16
        int id = (b - 1764) * 256 + tid;
        #pragma unroll
        for (int j = 0; j < 4; ++j) {
            int e = id + j * 8192;
            float4 v = ((const float4*)Wf2)[e];
            bf16x4 o2 = {(__bf16)v.x, (__bf16)v.y, (__bf16)v.z, (__bf16)v.w};
            ((bf16x4*)Wf2c)[e] = o2;
        }
    } else {                              // h0 nonzero bitmask
        __shared__ unsigned sm[32];
        if (tid < 32) sm[tid] = 0u;
        __syncthreads();
        unsigned nib = 0;
        #pragma unroll
        for (int j = 0; j < 4; ++j) {
            int d = tid * 4 + j;
            const uint4* hu = (const uint4*)(h0 + d * NDIM);
            uint4 a0 = hu[0], a1 = hu[1], a2 = hu[2], a3 = hu[3];
            unsigned nz = a0.x | a0.y | a0.z | a0.w | a1.x | a1.y | a1.z | a1.w |
                          a2.x | a2.y | a2.z | a2.w | a3.x | a3.y | a3.z | a3.w;
            if (nz) nib |= (1u << j);
        }
        if (nib) atomicOr(&sm[(tid * 4) >> 5], nib << ((tid * 4) & 31));
        __syncthreads();
        if (tid < 32) h0mask[tid] = sm[tid];
    }
}

// ---------------------------------------------------------------------------
// Core BMxBN MFMA GEMM, templated BK/NBUF. XOR swizzle both sides.
// ACT: 1 relu(+prev), 2 fast-tanh, 4 split128-relu, 7 pair-scatter raw (Gpre)
// ---------------------------------------------------------------------------
template <int BM, int BN, int BK, int NBUF, int ACT, bool ADD_PREV, bool GUARDN, bool AF32>
__device__ __forceinline__ void gemm_core(
    const void* Av, int lda, const __bf16* __restrict__ Bt, int ldb, int Ntot,
    const float* __restrict__ bias, const __bf16* __restrict__ prev, int ldp,
    __bf16* __restrict__ C, int ldc, int K, int bm, int bn,
    __bf16* As, __bf16* Bs) {
    constexpr int WM = BM / 2, WN = BN / 2, FM = WM / 16, FN = WN / 16;
    constexpr int ASZ = BM * BK, BSZ = BN * BK;
    constexpr int CPR = BK / 8;
    constexpr int NH = BK / 32;
    const int tid = threadIdx.x;
    const int lane = tid & 63, w = tid >> 6;
    const int wr = w >> 1, wc = w & 1;
    const int g = lane >> 4, lr = lane & 15;
    const __bf16* A16 = (const __bf16*)Av;
    const float* A32 = (const float*)Av;

    auto stage = [&](int buf, int k0) {
        #pragma unroll
        for (int i = 0; i < BM * BK / 2048; ++i) {
            int D = i * 256 + tid;
            int row = D / CPR, pos = D % CPR, c = pos ^ (row & 7);
            if constexpr (AF32) {
                const float* s = &A32[(size_t)(bm + row) * lda + k0 + c * 8];
                float4 v0 = *(const float4*)s;
                float4 v1 = *(const float4*)(s + 4);
                bf16x8 pk = {(__bf16)v0.x, (__bf16)v0.y, (__bf16)v0.z, (__bf16)v0.w,
                             (__bf16)v1.x, (__bf16)v1.y, (__bf16)v1.z, (__bf16)v1.w};
                *(bf16x8*)&As[buf * ASZ + row * BK + pos * 8] = pk;
            } else {
                glds16(&A16[(size_t)(bm + row) * lda + k0 + c * 8],
                       &As[buf * ASZ + (i * 256 + w * 64) * 8]);
            }
        }
        #pragma unroll
        for (int i = 0; i < BN * BK / 2048; ++i) {
            int D = i * 256 + tid;
            int row = D / CPR, pos = D % CPR, c = pos ^ (row & 7);
            glds16(&Bt[(size_t)(bn + row) * ldb + k0 + c * 8],
                   &Bs[buf * BSZ + (i * 256 + w * 64) * 8]);
        }
    };

    f32x4 acc[FM][FN] = {};
    const int x7 = lr & 7;
    int ca[NH];
    #pragma unroll
    for (int h = 0; h < NH; ++h) ca[h] = ((h * 4 + g) ^ x7) * 8;
    const int arow0 = wr * WM + lr;
    const int brow0 = wc * WN + lr;

    const int nt = K / BK;
    stage(0, 0);
    __syncthreads();
    for (int t = 0; t < nt; ++t) {
        if (NBUF == 2 && t + 1 < nt) stage((t + 1) & 1, (t + 1) * BK);
        const __bf16* Ab = &As[(NBUF == 2 ? (t & 1) : 0) * ASZ];
        const __bf16* Bb = &Bs[(NBUF == 2 ? (t & 1) : 0) * BSZ];
        bf16x8 af[FM][NH], bfr[FN][NH];
        #pragma unroll
        for (int m = 0; m < FM; ++m)
            #pragma unroll
            for (int h = 0; h < NH; ++h)
                af[m][h] = *(const bf16x8*)&Ab[(arow0 + m * 16) * BK + ca[h]];
        #pragma unroll
        for (int n = 0; n < FN; ++n)
            #pragma unroll
            for (int h = 0; h < NH; ++h)
                bfr[n][h] = *(const bf16x8*)&Bb[(brow0 + n * 16) * BK + ca[h]];
        #pragma unroll
        for (int h = 0; h < NH; ++h)
            #pragma unroll
            for (int m = 0; m < FM; ++m)
                #pragma unroll
                for (int n = 0; n < FN; ++n)
                    acc[m][n] = __builtin_amdgcn_mfma_f32_16x16x32_bf16(
                        af[m][h], bfr[n][h], acc[m][n], 0, 0, 0);
        __syncthreads();
    }

    #pragma unroll
    for (int m = 0; m < FM; ++m) {
        #pragma unroll
        for (int n = 0; n < FN; ++n) {
            #pragma unroll
            for (int r = 0; r < 4; ++r) {
                int grow = bm + wr * WM + m * 16 + g * 4 + r;
                int gcol = bn + wc * WN + n * 16 + lr;
                if (!GUARDN || gcol < Ntot) {
                    float v = acc[m][n][r];
                    int orow = grow;
                    if (ACT == 1) {
                        v += bias[gcol];
                        if (ADD_PREV) v += (float)prev[(size_t)grow * ldp + gcol];
                        v = fmaxf(v, 0.f);
                    } else if (ACT == 2) {
                        v += bias[gcol];
                        float e = __expf(2.f * v);
                        v = 1.f - 2.f * __builtin_amdgcn_rcpf(e + 1.f);
                    } else if (ACT == 4) {
                        if (gcol < HDIM) v = fmaxf(v + bias[gcol], 0.f);
                    } else if (ACT == 7) { // Gpre pair-scatter, raw
                        orow = (grow < 1024) ? slot_de(grow) : 2048 + (grow - 1024);
                    }
                    C[(size_t)orow * ldc + gcol] = (__bf16)v;
                }
            }
        }
    }
}

// ---------------------------------------------------------------------------
// stage2: [0,68) Gpre FIRST (longest per-block -> shortest tail);
// [68,580) G1 (x fp32 reg-staged, BK=128); [580,844) bias fold.
// ---------------------------------------------------------------------------
__global__ __launch_bounds__(256) void stage2_k(
    const float* __restrict__ x, const __bf16* __restrict__ WaT,
    const __bf16* __restrict__ WbigT, const __bf16* __restrict__ Wf2c,
    const float* __restrict__ bf2, const float* __restrict__ b1,
    const float* __restrict__ b2, const float* __restrict__ b3,
    const float* __restrict__ bl1,
    __bf16* __restrict__ tmp12, __bf16* __restrict__ WpairT,
    float* __restrict__ bias_pair) {
    __shared__ __bf16 As[8192];
    __shared__ __bf16 Bs[16384];
    const int b = blockIdx.x;
    if (b < 68) {
        // Gpre: Wcomb cols scattered into WpairT delta/BC slots  M=1088 N=128 K=1024
        const int bm = (b >> 1) * 32, bn = (b & 1) * 64;
        gemm_core<32, 64, 128, 2, 7, false, false, false>(
            WbigT, 1024, Wf2c, 1024, 128, nullptr, nullptr, 0,
            WpairT, 128, 1024, bm, bn, As, Bs);
    } else if (b < 580) {
        // G1: tmp12 = [relu(x@Wl1+bl1) | x@Wf1_top]  M=4096 N=256 K=1024
        const int lb = b - 68;
        const int aid = (lb & 7) * 64 + (lb >> 3);
        const int bn = (aid & 3) * 64, bm = (aid >> 2) * 32;
        gemm_core<32, 64, 128, 2, 4, false, false, true>(
            x, DDIM, WaT, 1024, 256, bl1, nullptr, 0, tmp12, 256, 1024, bm, bn, As, Bs);
    } else {
        // bias fold: fold(n) = ball[n] + sum_d bf2[d]*Wall[d][n] -> pair/BC slots
        const int n = (b - 580) * 4 + (threadIdx.x >> 6);
        const int lane = threadIdx.x & 63;
        const __bf16* wr = WbigT + (size_t)n * 1024 + lane * 16;
        float s = 0.f;
        #pragma unroll
        for (int i = 0; i < 2; ++i) {
            bf16x8 wv = *(const bf16x8*)&wr[i * 8];
            float4 f0 = *(const float4*)&bf2[lane * 16 + i * 8];
            float4 f1 = *(const float4*)&bf2[lane * 16 + i * 8 + 4];
            s += (float)wv[0] * f0.x + (float)wv[1] * f0.y + (float)wv[2] * f0.z +
                 (float)wv[3] * f0.w + (float)wv[4] * f1.x + (float)wv[5] * f1.y +
                 (float)wv[6] * f1.z + (float)wv[7] * f1.w;
        }
        #pragma unroll
        for (int off = 32; off; off >>= 1) s += __shfl_down(s, off);
        if (lane == 0) {
            float base = (n < DDIM) ? b1[n]
                       : (n < DDIM + NDIM) ? b2[n - DDIM] : b3[n - DDIM - NDIM];
            int sl = (n < DDIM) ? slot_de(n) : 2048 + (n - DDIM);
            bias_pair[sl] = base + s;
        }
    }
}

// ---------------------------------------------------------------------------
// g23_k: fused G2+G3. Per block: 16 tmp2 rows; loop kc over 1024 in 128s:
//   lifted_c = tanh(t1 @ Wl2[:,kc:kc+128]) -> LDS (swizzled) ->
//   acc2 += lifted_c @ Wf1b[kc:kc+128, :]
// 256 blocks x 512 thr (8 waves). LDS 139 KB, 1 blk/CU.
// ---------------------------------------------------------------------------
__global__ __launch_bounds__(512) void g23_k(
    const __bf16* __restrict__ tmp12, const __bf16* __restrict__ Wl2T,
    const __bf16* __restrict__ Wf1bT, const float* __restrict__ bl2,
    const float* __restrict__ bf1, __bf16* __restrict__ tmp2) {
    __shared__ __bf16 T1[2048];
    __shared__ __bf16 LS[2048];
    __shared__ __bf16 B1[2][16384];
    __shared__ __bf16 B2[2][16384];
    const int tid = threadIdx.x;
    const int lane = tid & 63, w = tid >> 6;
    const int g = lane >> 4, lr = lane & 15;
    const int x7 = lr & 7;
    const int bm = blockIdx.x * 16;

    if (tid < 256) {
        int row = tid >> 4, pos = tid & 15, c = pos ^ (row & 7);
        glds16(&tmp12[(size_t)(bm + row) * 256 + c * 8], &T1[w * 512]);
    }
    auto stageB = [&](int buf, int kc) {
        #pragma unroll
        for (int i = 0; i < 4; ++i) {
            int D = i * 512 + tid;
            int row = D >> 4, pos = D & 15, c = pos ^ (row & 7);
            glds16(&Wl2T[(size_t)(kc + row) * 128 + c * 8],
                   &B1[buf][(i * 512 + w * 64) * 8]);
            glds16(&Wf1bT[(size_t)row * 1024 + kc + c * 8],
                   &B2[buf][(i * 512 + w * 64) * 8]);
        }
    };

    int ca[4];
    #pragma unroll
    for (int h = 0; h < 4; ++h) ca[h] = ((h * 4 + g) ^ x7) * 8;
    const int col = w * 16 + lr;
    const int brow = col * 128;

    stageB(0, 0);
    __syncthreads();
    bf16x8 a1[4];
    #pragma unroll
    for (int h = 0; h < 4; ++h) a1[h] = *(const bf16x8*)&T1[lr * 128 + ca[h]];

    f32x4 acc2 = {};
    for (int t = 0; t < 8; ++t) {
        if (t + 1 < 8) stageB((t + 1) & 1, (t + 1) * 128);
        const __bf16* b1b = B1[t & 1];
        const __bf16* b2b = B2[t & 1];
        f32x4 acc1 = {};
        #pragma unroll
        for (int h = 0; h < 4; ++h) {
            bf16x8 bf = *(const bf16x8*)&b1b[brow + ca[h]];
            acc1 = __builtin_amdgcn_mfma_f32_16x16x32_bf16(a1[h], bf, acc1, 0, 0, 0);
        }
        const float bl = bl2[t * 128 + col];
        const int chunk = col >> 3, cin = col & 7;
        #pragma unroll
        for (int r = 0; r < 4; ++r) {
            float v = acc1[r] + bl;
            float e = __expf(2.f * v);
            v = 1.f - 2.f * __builtin_amdgcn_rcpf(e + 1.f);  // tanh
            int row = g * 4 + r;
            LS[row * 128 + ((chunk ^ (row & 7)) << 3) + cin] = (__bf16)v;
        }
        __syncthreads();
        #pragma unroll
        for (int h = 0; h < 4; ++h) {
            bf16x8 a2 = *(const bf16x8*)&LS[lr * 128 + ca[h]];
            bf16x8 bf = *(const bf16x8*)&b2b[brow + ca[h]];
            acc2 = __builtin_amdgcn_mfma_f32_16x16x32_bf16(a2, bf, acc2, 0, 0, 0);
        }
        __syncthreads();
    }

    const float bfv = bf1[col];
    #pragma unroll
    for (int r = 0; r < 4; ++r) {
        const int row = g * 4 + r;
        float v = acc2[r] + bfv + (float)tmp12[(size_t)(bm + row) * 256 + 128 + col];
        v = fmaxf(v, 0.f);
        tmp2[(size_t)(bm + row) * 128 + col] = (__bf16)v;
    }
}

// ---------------------------------------------------------------------------
// mm_pairs: [xt|de] pair GEMM + in-kernel BC (Bm/Cm/cb) + final epilogue.
// M=4096 N=2048 K=128. BM=128 BN=64, 1024 blocks, LDS 48 KB.
// ---------------------------------------------------------------------------
__global__ __launch_bounds__(256) void mm_pairs(
    const __bf16* __restrict__ tmp2, const __bf16* __restrict__ WpairT,
    const float* __restrict__ bias_pair,
    const float* __restrict__ Amat, const float* __restrict__ h0,
    const unsigned* __restrict__ h0mask,
    float* __restrict__ out, float* __restrict__ last_h) {
    constexpr int ASZ = 128 * 64, BSZ = 64 * 64;
    __shared__ __bf16 As[2 * ASZ];
    __shared__ __bf16 Bs[2 * BSZ];
    const int NB = gridDim.x; // 1024
    const int aid = (blockIdx.x & 7) * (NB >> 3) + (blockIdx.x >> 3);
    const int bn = (aid & 31) * 64, bm = (aid >> 5) * 128;
    const int tid = threadIdx.x;
    const int lane = tid & 63, w = tid >> 6;
    const int wr = w >> 1, wc = w & 1;
    const int g = lane >> 4, lr = lane & 15;

    auto stage = [&](int buf, int k0) {
        #pragma unroll
        for (int i = 0; i < 4; ++i) {
            int D = i * 256 + tid;
            int row = D >> 3, pos = D & 7, c = pos ^ (row & 7);
            glds16(&tmp2[(size_t)(bm + row) * 128 + k0 + c * 8],
                   &As[buf * ASZ + (i * 256 + w * 64) * 8]);
        }
        #pragma unroll
        for (int i = 0; i < 2; ++i) {
            int D = i * 256 + tid;
            int row = D >> 3, pos = D & 7, c = pos ^ (row & 7);
            glds16(&WpairT[(size_t)(bn + row) * 128 + k0 + c * 8],
                   &Bs[buf * BSZ + (i * 256 + w * 64) * 8]);
        }
    };

    f32x4 acc[4][2] = {};
    const int x7 = lr & 7;
    const int ca[2] = {(g ^ x7) * 8, ((4 + g) ^ x7) * 8};
    const int arow0 = wr * 64 + lr, brow0 = wc * 32 + lr;
    stage(0, 0);
    __syncthreads();
    #pragma unroll
    for (int t = 0; t < 2; ++t) {
        if (t == 0) stage(1, 64);
        const __bf16* Ab = &As[t * ASZ];
        const __bf16* Bb = &Bs[t * BSZ];
        bf16x8 af[4][2], bfr[2][2];
        #pragma unroll
        for (int m = 0; m < 4; ++m)
            #pragma unroll
            for (int h = 0; h < 2; ++h)
                af[m][h] = *(const bf16x8*)&Ab[(arow0 + m * 16) * 64 + ca[h]];
        #pragma unroll
        for (int n = 0; n < 2; ++n)
            #pragma unroll
            for (int h = 0; h < 2; ++h)
                bfr[n][h] = *(const bf16x8*)&Bb[(brow0 + n * 16) * 64 + ca[h]];
        #pragma unroll
        for (int h = 0; h < 2; ++h)
            #pragma unroll
            for (int m = 0; m < 4; ++m)
                #pragma unroll
                for (int n = 0; n < 2; ++n)
                    acc[m][n] = __builtin_amdgcn_mfma_f32_16x16x32_bf16(
                        af[m][h], bfr[n][h], acc[m][n], 0, 0, 0);
        __syncthreads();
    }

    // in-kernel BC
    {
        int row = tid >> 3, pos = tid & 7, c = pos ^ (row & 7);
        #pragma unroll
        for (int t2 = 0; t2 < 2; ++t2)
            glds16(&WpairT[(size_t)(2048 + row) * 128 + t2 * 64 + c * 8],
                   &Bs[t2 * 2048 + w * 512]);
    }
    __syncthreads();
    f32x4 accB[2] = {}, accC[2] = {};
    #pragma unroll
    for (int t2 = 0; t2 < 2; ++t2) {
        const __bf16* Ab = &As[t2 * ASZ];
        #pragma unroll
        for (int h = 0; h < 2; ++h) {
            bf16x8 bB = *(const bf16x8*)&Bs[t2 * 2048 + lr * 64 + ca[h]];
            bf16x8 bC = *(const bf16x8*)&Bs[t2 * 2048 + (16 + lr) * 64 + ca[h]];
            #pragma unroll
            for (int m2 = 0; m2 < 2; ++m2) {
                bf16x8 a2 = *(const bf16x8*)&Ab[(w * 32 + m2 * 16 + lr) * 64 + ca[h]];
                accB[m2] = __builtin_amdgcn_mfma_f32_16x16x32_bf16(a2, bB, accB[m2], 0, 0, 0);
                accC[m2] = __builtin_amdgcn_mfma_f32_16x16x32_bf16(a2, bC, accC[m2], 0, 0, 0);
            }
        }
    }
    __syncthreads();
    float* sCB = (float*)As;
    __bf16* sBC = &Bs[BSZ];
    const float bB_ = bias_pair[2048 + lr], bC_ = bias_pair[2064 + lr];
    #pragma unroll
    for (int m2 = 0; m2 < 2; ++m2) {
        #pragma unroll
        for (int r = 0; r < 4; ++r) {
            int lrow = w * 32 + m2 * 16 + g * 4 + r;
            float vB = accB[m2][r] + bB_;
            float vC = accC[m2][r] + bC_;
            sBC[lrow * 32 + lr] = (__bf16)vB;
            sBC[lrow * 32 + 16 + lr] = (__bf16)vC;
            float p = vB * vC;
            #pragma unroll
            for (int m3 = 1; m3 < 16; m3 <<= 1) p += __shfl_xor(p, m3);
            if (lr == 0) sCB[lrow] = p;
        }
    }
    __syncthreads();

    const int d = ((bn + wc * 32) >> 1) + lr;
    const float bx_ = bias_pair[bn + wc * 32 + lr];
    const float bd_ = bias_pair[bn + wc * 32 + 16 + lr];
    const bool msk = (h0mask[d >> 5] >> (d & 31)) & 1u;
    #pragma unroll
    for (int m = 0; m < 4; ++m) {
        #pragma unroll
        for (int r = 0; r < 4; ++r) {
            const int lrow = wr * 64 + m * 16 + g * 4 + r;
            const int row = bm + lrow;
            const float xt = acc[m][0][r] + bx_;
            const float dr = acc[m][1][r] + bd_;
            const float e = __expf(-fabsf(dr));
            const float de = fmaxf(dr, 0.f) + __logf(1.f + e);
            const float xd = xt * de;
            float res = xd * sCB[lrow];
            const bool is_last = (row & (LSEQ - 1)) == (LSEQ - 1);
            if (msk) {
                float s = 0.f;
                #pragma unroll
                for (int n = 0; n < NDIM; ++n) {
                    float z = de * Amat[d * NDIM + n];
                    float c2 = (z > 0.f) ? z : __expf(z) - 1.f;
                    float da = __expf(-c2);
                    float h0v = h0[d * NDIM + n];
                    s += (float)sBC[lrow * 32 + 16 + n] * da * h0v;
                    if (is_last)
                        last_h[(((size_t)(row >> 11)) * DDIM + d) * NDIM + n] =
                            da * h0v + xd * (float)sBC[lrow * 32 + n];
                }
                res += s;
            } else if (is_last) {
                #pragma unroll
                for (int n = 0; n < NDIM; ++n)
                    last_h[(((size_t)(row >> 11)) * DDIM + d) * NDIM + n] =
                        xd * (float)sBC[lrow * 32 + n];
            }
            out[(size_t)row * DDIM + d] = res;
        }
    }
}

extern "C" void kernel_launch(void* const* d_in, const int* in_sizes, int n_in,
                              void* d_out, int out_size, void* d_ws, size_t ws_size,
                              hipStream_t stream) {
    const float* x   = (const float*)d_in[0];
    const float* W1  = (const float*)d_in[1];
    const float* b1  = (const float*)d_in[2];
    const float* W2  = (const float*)d_in[3];
    const float* b2  = (const float*)d_in[4];
    const float* W3  = (const float*)d_in[5];
    const float* b3  = (const float*)d_in[6];
    const float* Wl1 = (const float*)d_in[7];
    const float* bl1 = (const float*)d_in[8];
    const float* Wl2 = (const float*)d_in[9];
    const float* bl2 = (const float*)d_in[10];
    const float* Wf1 = (const float*)d_in[11];
    const float* bf1 = (const float*)d_in[12];
    const float* Wf2 = (const float*)d_in[13];
    const float* bf2 = (const float*)d_in[14];
    const float* h0  = (const float*)d_in[15];
    const float* Amat= (const float*)d_in[16];

    float* out    = (float*)d_out;
    float* last_h = (float*)d_out + (size_t)MROWS * DDIM;

    __bf16* wsb = (__bf16*)d_ws;
    size_t o = 0;
    auto alloc = [&](size_t n) { __bf16* p = wsb + o; o += n; return p; };
    __bf16* WaT    = alloc(256 * 1024);             // [Wl1 | Wf1_top]^T
    __bf16* Wf1bT  = alloc(128 * 1024);
    __bf16* Wl2T   = alloc(1024 * 128);
    __bf16* WbigT  = alloc((size_t)NPAD * 1024);    // [W1 | W2 | W3 | pad]^T
    __bf16* WpairT = alloc(2112 * 128);             // pairs 0..2047, BC 2048..2079
    __bf16* Wf2c   = alloc(128 * 1024);             // Wf2 bf16 row-major
    __bf16* tmp12  = alloc((size_t)MROWS * 256);    // [relu(x@Wl1+bl1) | x@Wf1_top]
    __bf16* tmp2   = alloc((size_t)MROWS * HDIM);
    float*  bias_pair = (float*)(wsb + o); o += 2 * 2112;
    unsigned* h0mask = (unsigned*)(wsb + o);

    // 1. pack (flat 1797 blocks)
    pack_all<<<dim3(1797), 256, 0, stream>>>(W1, W2, W3, Wl1, Wl2, Wf1, Wf2,
                                             bf2, h0,
                                             WbigT, WaT, Wf1bT, Wl2T, WpairT,
                                             Wf2c, bias_pair, h0mask);
    // 2. stage2: Gpre (68, first = shortest tail) + G1 (512) + bias fold (264)
    stage2_k<<<dim3(844), 256, 0, stream>>>(x, WaT, WbigT, Wf2c, bf2, b1, b2, b3,
                                            bl1, tmp12, WpairT, bias_pair);
    // 3. g23: fused G2+G3 -> tmp2 (lifted never materialized)
    g23_k<<<dim3(256), 512, 0, stream>>>(tmp12, Wl2T, Wf1bT, bl2, bf1, tmp2);
    // 4. mm_pairs: fused [x_tr|delta] GEMM + BC + final epilogue -> out, last_h
    mm_pairs<<<dim3(32 * 32), 256, 0, stream>>>(tmp2, WpairT, bias_pair,
                                                Amat, h0, h0mask, out, last_h);
}

// Round 18
// 50.230 us; speedup vs baseline: 1.1600x; 1.0296x over previous
//
#include <hip/hip_runtime.h>
#include <cmath>

#define B_SZ 2
#define LSEQ 2048
#define DDIM 1024
#define NDIM 16
#define HDIM 128
#define MROWS (B_SZ * LSEQ)    // 4096
#define NBIG (DDIM + 2 * NDIM) // 1056
#define NPAD 1088              // NBIG padded to 64

typedef __bf16 bf16x8 __attribute__((ext_vector_type(8)));
typedef __bf16 bf16x4 __attribute__((ext_vector_type(4)));
typedef float f32x4 __attribute__((ext_vector_type(4)));

// async global->LDS, 16B/lane; LDS dest = wave-uniform base + lane*16
__device__ __forceinline__ void glds16(const __bf16* g, __bf16* l) {
    __builtin_amdgcn_global_load_lds(
        (const __attribute__((address_space(1))) unsigned int*)g,
        (__attribute__((address_space(3))) unsigned int*)l, 16, 0, 0);
}

// pair-layout row slots
__device__ __forceinline__ int slot_xt(int d) { return (d >> 4) * 32 + (d & 15); }
__device__ __forceinline__ int slot_de(int d) { return (d >> 4) * 32 + 16 + (d & 15); }

// ---------------------------------------------------------------------------
// Preprocessing (flat 1-D grid, 1797 blocks).
// ---------------------------------------------------------------------------
__device__ __forceinline__ void tcast_tile(const float* __restrict__ in,
                                           __bf16* __restrict__ out, int K, int N,
                                           int bx, int by, float (*t)[33]) {
    int tx = threadIdx.x & 31, ty = threadIdx.x >> 5;
    int n0 = bx * 32, k0 = by * 32;
    #pragma unroll
    for (int i = 0; i < 4; ++i) {
        int k = k0 + ty + i * 8, n = n0 + tx;
        t[ty + i * 8][tx] = (k < K && n < N) ? in[(size_t)k * N + n] : 0.f;
    }
    __syncthreads();
    #pragma unroll
    for (int i = 0; i < 4; ++i) {
        int n = n0 + ty + i * 8, k = k0 + tx;
        if (n < N && k < K) out[(size_t)n * K + k] = (__bf16)t[tx][ty + i * 8];
    }
}

// Wf2 [128][1024] -> WpairT xt slots (row slot_xt(n), ld 128)
__device__ __forceinline__ void tcast_pair_tile(const float* __restrict__ in,
                                                __bf16* __restrict__ out,
                                                int bx, int by, float (*t)[33]) {
    int tx = threadIdx.x & 31, ty = threadIdx.x >> 5;
    int n0 = bx * 32, k0 = by * 32;
    #pragma unroll
    for (int i = 0; i < 4; ++i) {
        int k = k0 + ty + i * 8, n = n0 + tx;
        t[ty + i * 8][tx] = in[(size_t)k * 1024 + n];
    }
    __syncthreads();
    #pragma unroll
    for (int i = 0; i < 4; ++i) {
        int n = n0 + ty + i * 8, k = k0 + tx;
        out[(size_t)slot_xt(n) * 128 + k] = (__bf16)t[tx][ty + i * 8];
    }
}

__global__ __launch_bounds__(256) void pack_all(
    const float* W1, const float* W2, const float* W3, const float* Wl1,
    const float* Wl2, const float* Wf1, const float* Wf2,
    const float* bf2, const float* h0,
    __bf16* WbigT, __bf16* WaT, __bf16* Wf1bT, __bf16* Wl2T, __bf16* WpairT,
    __bf16* Wf2c, float* bias_pair, unsigned* h0mask) {
    __shared__ float t[32][33];
    const int b = blockIdx.x;
    const int tid = threadIdx.x;
    if (b < 1024) {                       // W1 -> WbigT
        tcast_tile(W1, WbigT, 1024, 1024, b & 31, b >> 5, t);
    } else if (b < 1152) {                // Wl1 -> WaT
        int i = b - 1024; tcast_tile(Wl1, WaT, 1024, 128, i & 3, i >> 2, t);
    } else if (b < 1280) {                // Wf1 top -> WaT[128k..]
        int i = b - 1152; tcast_tile(Wf1, WaT + 128 * 1024, 1024, 128, i & 3, i >> 2, t);
    } else if (b < 1408) {                // Wf1 bottom -> Wf1bT
        int i = b - 1280;
        tcast_tile(Wf1 + (size_t)1024 * 128, Wf1bT, 1024, 128, i & 3, i >> 2, t);
    } else if (b < 1536) {                // Wl2 -> Wl2T
        int i = b - 1408; tcast_tile(Wl2, Wl2T, 128, 1024, i & 31, i >> 5, t);
    } else if (b < 1664) {                // Wf2 -> WpairT xt slots
        int i = b - 1536; tcast_pair_tile(Wf2, WpairT, i & 31, i >> 5, t);
    } else if (b < 1696) {                // W2 -> WbigT[1024..]
        int i = b - 1664; tcast_tile(W2, WbigT + (size_t)1024 * 1024, 1024, 16, 0, i, t);
    } else if (b < 1728) {                // W3 -> WbigT[1040..]
        int i = b - 1696; tcast_tile(W3, WbigT + (size_t)1040 * 1024, 1024, 16, 0, i, t);
    } else if (b < 1732) {                // xt bias scatter
        int i = (b - 1728) * 256 + tid;
        bias_pair[slot_xt(i)] = bf2[i];
    } else if (b < 1764) {                // zero WbigT pad rows
        int i = (b - 1732) * 256 + tid;
        #pragma unroll
        for (int r = 0; r < 4; ++r) {
            int e = i + r * 8192;
            if (e < 32 * 1024) WbigT[(size_t)1056 * 1024 + e] = (__bf16)0.f;
        }
    } else if (b < 1796) {                // Wf2 -> Wf2c row-major bf16
        int id = (b - 1764) * 256 + tid;
        #pragma unroll
        for (int j = 0; j < 4; ++j) {
            int e = id + j * 8192;
            float4 v = ((const float4*)Wf2)[e];
            bf16x4 o2 = {(__bf16)v.x, (__bf16)v.y, (__bf16)v.z, (__bf16)v.w};
            ((bf16x4*)Wf2c)[e] = o2;
        }
    } else {                              // h0 nonzero bitmask
        __shared__ unsigned sm[32];
        if (tid < 32) sm[tid] = 0u;
        __syncthreads();
        unsigned nib = 0;
        #pragma unroll
        for (int j = 0; j < 4; ++j) {
            int d = tid * 4 + j;
            const uint4* hu = (const uint4*)(h0 + d * NDIM);
            uint4 a0 = hu[0], a1 = hu[1], a2 = hu[2], a3 = hu[3];
            unsigned nz = a0.x | a0.y | a0.z | a0.w | a1.x | a1.y | a1.z | a1.w |
                          a2.x | a2.y | a2.z | a2.w | a3.x | a3.y | a3.z | a3.w;
            if (nz) nib |= (1u << j);
        }
        if (nib) atomicOr(&sm[(tid * 4) >> 5], nib << ((tid * 4) & 31));
        __syncthreads();
        if (tid < 32) h0mask[tid] = sm[tid];
    }
}

// ---------------------------------------------------------------------------
// Core BMxBN MFMA GEMM, templated BK/NBUF. XOR swizzle both sides.
// ACT: 1 relu(+prev), 2 fast-tanh, 4 split128-relu, 7 pair-scatter raw (Gpre)
// ---------------------------------------------------------------------------
template <int BM, int BN, int BK, int NBUF, int ACT, bool ADD_PREV, bool GUARDN, bool AF32>
__device__ __forceinline__ void gemm_core(
    const void* Av, int lda, const __bf16* __restrict__ Bt, int ldb, int Ntot,
    const float* __restrict__ bias, const __bf16* __restrict__ prev, int ldp,
    __bf16* __restrict__ C, int ldc, int K, int bm, int bn,
    __bf16* As, __bf16* Bs) {
    constexpr int WM = BM / 2, WN = BN / 2, FM = WM / 16, FN = WN / 16;
    constexpr int ASZ = BM * BK, BSZ = BN * BK;
    constexpr int CPR = BK / 8;
    constexpr int NH = BK / 32;
    const int tid = threadIdx.x;
    const int lane = tid & 63, w = tid >> 6;
    const int wr = w >> 1, wc = w & 1;
    const int g = lane >> 4, lr = lane & 15;
    const __bf16* A16 = (const __bf16*)Av;
    const float* A32 = (const float*)Av;

    auto stage = [&](int buf, int k0) {
        #pragma unroll
        for (int i = 0; i < BM * BK / 2048; ++i) {
            int D = i * 256 + tid;
            int row = D / CPR, pos = D % CPR, c = pos ^ (row & 7);
            if constexpr (AF32) {
                const float* s = &A32[(size_t)(bm + row) * lda + k0 + c * 8];
                float4 v0 = *(const float4*)s;
                float4 v1 = *(const float4*)(s + 4);
                bf16x8 pk = {(__bf16)v0.x, (__bf16)v0.y, (__bf16)v0.z, (__bf16)v0.w,
                             (__bf16)v1.x, (__bf16)v1.y, (__bf16)v1.z, (__bf16)v1.w};
                *(bf16x8*)&As[buf * ASZ + row * BK + pos * 8] = pk;
            } else {
                glds16(&A16[(size_t)(bm + row) * lda + k0 + c * 8],
                       &As[buf * ASZ + (i * 256 + w * 64) * 8]);
            }
        }
        #pragma unroll
        for (int i = 0; i < BN * BK / 2048; ++i) {
            int D = i * 256 + tid;
            int row = D / CPR, pos = D % CPR, c = pos ^ (row & 7);
            glds16(&Bt[(size_t)(bn + row) * ldb + k0 + c * 8],
                   &Bs[buf * BSZ + (i * 256 + w * 64) * 8]);
        }
    };

    f32x4 acc[FM][FN] = {};
    const int x7 = lr & 7;
    int ca[NH];
    #pragma unroll
    for (int h = 0; h < NH; ++h) ca[h] = ((h * 4 + g) ^ x7) * 8;
    const int arow0 = wr * WM + lr;
    const int brow0 = wc * WN + lr;

    const int nt = K / BK;
    stage(0, 0);
    __syncthreads();
    for (int t = 0; t < nt; ++t) {
        if (NBUF == 2 && t + 1 < nt) stage((t + 1) & 1, (t + 1) * BK);
        const __bf16* Ab = &As[(NBUF == 2 ? (t & 1) : 0) * ASZ];
        const __bf16* Bb = &Bs[(NBUF == 2 ? (t & 1) : 0) * BSZ];
        bf16x8 af[FM][NH], bfr[FN][NH];
        #pragma unroll
        for (int m = 0; m < FM; ++m)
            #pragma unroll
            for (int h = 0; h < NH; ++h)
                af[m][h] = *(const bf16x8*)&Ab[(arow0 + m * 16) * BK + ca[h]];
        #pragma unroll
        for (int n = 0; n < FN; ++n)
            #pragma unroll
            for (int h = 0; h < NH; ++h)
                bfr[n][h] = *(const bf16x8*)&Bb[(brow0 + n * 16) * BK + ca[h]];
        #pragma unroll
        for (int h = 0; h < NH; ++h)
            #pragma unroll
            for (int m = 0; m < FM; ++m)
                #pragma unroll
                for (int n = 0; n < FN; ++n)
                    acc[m][n] = __builtin_amdgcn_mfma_f32_16x16x32_bf16(
                        af[m][h], bfr[n][h], acc[m][n], 0, 0, 0);
        __syncthreads();
    }

    #pragma unroll
    for (int m = 0; m < FM; ++m) {
        #pragma unroll
        for (int n = 0; n < FN; ++n) {
            #pragma unroll
            for (int r = 0; r < 4; ++r) {
                int grow = bm + wr * WM + m * 16 + g * 4 + r;
                int gcol = bn + wc * WN + n * 16 + lr;
                if (!GUARDN || gcol < Ntot) {
                    float v = acc[m][n][r];
                    int orow = grow;
                    if (ACT == 1) {
                        v += bias[gcol];
                        if (ADD_PREV) v += (float)prev[(size_t)grow * ldp + gcol];
                        v = fmaxf(v, 0.f);
                    } else if (ACT == 2) {
                        v += bias[gcol];
                        float e = __expf(2.f * v);
                        v = 1.f - 2.f * __builtin_amdgcn_rcpf(e + 1.f);
                    } else if (ACT == 4) {
                        if (gcol < HDIM) v = fmaxf(v + bias[gcol], 0.f);
                    } else if (ACT == 7) { // Gpre pair-scatter, raw
                        orow = (grow < 1024) ? slot_de(grow) : 2048 + (grow - 1024);
                    }
                    C[(size_t)orow * ldc + gcol] = (__bf16)v;
                }
            }
        }
    }
}

// ---------------------------------------------------------------------------
// stage2: [0,68) Gpre FIRST; [68,580) G1 (x fp32 reg-staged, BK=128);
// [580,844) bias fold.
// ---------------------------------------------------------------------------
__global__ __launch_bounds__(256) void stage2_k(
    const float* __restrict__ x, const __bf16* __restrict__ WaT,
    const __bf16* __restrict__ WbigT, const __bf16* __restrict__ Wf2c,
    const float* __restrict__ bf2, const float* __restrict__ b1,
    const float* __restrict__ b2, const float* __restrict__ b3,
    const float* __restrict__ bl1,
    __bf16* __restrict__ tmp12, __bf16* __restrict__ WpairT,
    float* __restrict__ bias_pair) {
    __shared__ __bf16 As[8192];
    __shared__ __bf16 Bs[16384];
    const int b = blockIdx.x;
    if (b < 68) {
        // Gpre: Wcomb cols scattered into WpairT delta/BC slots  M=1088 N=128 K=1024
        const int bm = (b >> 1) * 32, bn = (b & 1) * 64;
        gemm_core<32, 64, 128, 2, 7, false, false, false>(
            WbigT, 1024, Wf2c, 1024, 128, nullptr, nullptr, 0,
            WpairT, 128, 1024, bm, bn, As, Bs);
    } else if (b < 580) {
        // G1: tmp12 = [relu(x@Wl1+bl1) | x@Wf1_top]  M=4096 N=256 K=1024
        const int lb = b - 68;
        const int aid = (lb & 7) * 64 + (lb >> 3);
        const int bn = (aid & 3) * 64, bm = (aid >> 2) * 32;
        gemm_core<32, 64, 128, 2, 4, false, false, true>(
            x, DDIM, WaT, 1024, 256, bl1, nullptr, 0, tmp12, 256, 1024, bm, bn, As, Bs);
    } else {
        // bias fold: fold(n) = ball[n] + sum_d bf2[d]*Wall[d][n] -> pair/BC slots
        const int n = (b - 580) * 4 + (threadIdx.x >> 6);
        const int lane = threadIdx.x & 63;
        const __bf16* wr = WbigT + (size_t)n * 1024 + lane * 16;
        float s = 0.f;
        #pragma unroll
        for (int i = 0; i < 2; ++i) {
            bf16x8 wv = *(const bf16x8*)&wr[i * 8];
            float4 f0 = *(const float4*)&bf2[lane * 16 + i * 8];
            float4 f1 = *(const float4*)&bf2[lane * 16 + i * 8 + 4];
            s += (float)wv[0] * f0.x + (float)wv[1] * f0.y + (float)wv[2] * f0.z +
                 (float)wv[3] * f0.w + (float)wv[4] * f1.x + (float)wv[5] * f1.y +
                 (float)wv[6] * f1.z + (float)wv[7] * f1.w;
        }
        #pragma unroll
        for (int off = 32; off; off >>= 1) s += __shfl_down(s, off);
        if (lane == 0) {
            float base = (n < DDIM) ? b1[n]
                       : (n < DDIM + NDIM) ? b2[n - DDIM] : b3[n - DDIM - NDIM];
            int sl = (n < DDIM) ? slot_de(n) : 2048 + (n - DDIM);
            bias_pair[sl] = base + s;
        }
    }
}

// ---------------------------------------------------------------------------
// g23_k: fused G2+G3, SINGLE-buffered B tiles -> 72 KB LDS -> 2 blocks/CU
// (TLP covers staging latency; barriers drain vmcnt anyway so double-buffer
// bought nothing within a block — m114 mechanism).
// Issue discipline: B2(t+1) after sync2 (drained by next sync1, used phase2);
// B1(t+1) after sync1 (drained at sync2, used next phase1).
// ---------------------------------------------------------------------------
__global__ __launch_bounds__(512) void g23_k(
    const __bf16* __restrict__ tmp12, const __bf16* __restrict__ Wl2T,
    const __bf16* __restrict__ Wf1bT, const float* __restrict__ bl2,
    const float* __restrict__ bf1, __bf16* __restrict__ tmp2) {
    __shared__ __bf16 T1[2048];       // t1 16x128 (swizzled chunks)
    __shared__ __bf16 LS[2048];       // lifted chunk 16x128 (swizzled)
    __shared__ __bf16 B1[16384];      // Wl2T rows [kc..kc+128) x 128 (single)
    __shared__ __bf16 B2[16384];      // Wf1bT rows [0,128) x [kc..kc+128) (single)
    const int tid = threadIdx.x;
    const int lane = tid & 63, w = tid >> 6;
    const int g = lane >> 4, lr = lane & 15;
    const int x7 = lr & 7;
    const int bm = blockIdx.x * 16;

    if (tid < 256) {
        int row = tid >> 4, pos = tid & 15, c = pos ^ (row & 7);
        glds16(&tmp12[(size_t)(bm + row) * 256 + c * 8], &T1[w * 512]);
    }
    auto stageB1 = [&](int kc) {
        #pragma unroll
        for (int i = 0; i < 4; ++i) {
            int D = i * 512 + tid;
            int row = D >> 4, pos = D & 15, c = pos ^ (row & 7);
            glds16(&Wl2T[(size_t)(kc + row) * 128 + c * 8],
                   &B1[(i * 512 + w * 64) * 8]);
        }
    };
    auto stageB2 = [&](int kc) {
        #pragma unroll
        for (int i = 0; i < 4; ++i) {
            int D = i * 512 + tid;
            int row = D >> 4, pos = D & 15, c = pos ^ (row & 7);
            glds16(&Wf1bT[(size_t)row * 1024 + kc + c * 8],
                   &B2[(i * 512 + w * 64) * 8]);
        }
    };

    int ca[4];
    #pragma unroll
    for (int h = 0; h < 4; ++h) ca[h] = ((h * 4 + g) ^ x7) * 8;
    const int col = w * 16 + lr;      // this thread's output column (0..127)
    const int brow = col * 128;

    stageB1(0);
    stageB2(0);
    __syncthreads();
    bf16x8 a1[4];
    #pragma unroll
    for (int h = 0; h < 4; ++h) a1[h] = *(const bf16x8*)&T1[lr * 128 + ca[h]];

    f32x4 acc2 = {};
    for (int t = 0; t < 8; ++t) {
        // phase1: lifted_c[:, col] from B1 (current)
        f32x4 acc1 = {};
        #pragma unroll
        for (int h = 0; h < 4; ++h) {
            bf16x8 bf = *(const bf16x8*)&B1[brow + ca[h]];
            acc1 = __builtin_amdgcn_mfma_f32_16x16x32_bf16(a1[h], bf, acc1, 0, 0, 0);
        }
        const float bl = bl2[t * 128 + col];
        const int chunk = col >> 3, cin = col & 7;
        #pragma unroll
        for (int r = 0; r < 4; ++r) {
            float v = acc1[r] + bl;
            float e = __expf(2.f * v);
            v = 1.f - 2.f * __builtin_amdgcn_rcpf(e + 1.f);  // tanh
            int row = g * 4 + r;
            LS[row * 128 + ((chunk ^ (row & 7)) << 3) + cin] = (__bf16)v;
        }
        __syncthreads();                 // sync1: LS visible; B1/B2 reads done
        if (t + 1 < 8) stageB1((t + 1) * 128);  // in flight across phase2
        // phase2: acc2 += lifted_c @ Wf1b-chunk from B2 (current)
        #pragma unroll
        for (int h = 0; h < 4; ++h) {
            bf16x8 a2 = *(const bf16x8*)&LS[lr * 128 + ca[h]];
            bf16x8 bf = *(const bf16x8*)&B2[brow + ca[h]];
            acc2 = __builtin_amdgcn_mfma_f32_16x16x32_bf16(a2, bf, acc2, 0, 0, 0);
        }
        __syncthreads();                 // sync2: drains B1(t+1); B2/LS free
        if (t + 1 < 8) stageB2((t + 1) * 128);  // drained by next sync1
    }

    const float bfv = bf1[col];
    #pragma unroll
    for (int r = 0; r < 4; ++r) {
        const int row = g * 4 + r;
        float v = acc2[r] + bfv + (float)tmp12[(size_t)(bm + row) * 256 + 128 + col];
        v = fmaxf(v, 0.f);
        tmp2[(size_t)(bm + row) * 128 + col] = (__bf16)v;
    }
}

// ---------------------------------------------------------------------------
// mm_pairs: [xt|de] pair GEMM + in-kernel BC (Bm/Cm/cb) + final epilogue.
// M=4096 N=2048 K=128. BM=128 BN=64, 1024 blocks, LDS 48 KB.
// ---------------------------------------------------------------------------
__global__ __launch_bounds__(256) void mm_pairs(
    const __bf16* __restrict__ tmp2, const __bf16* __restrict__ WpairT,
    const float* __restrict__ bias_pair,
    const float* __restrict__ Amat, const float* __restrict__ h0,
    const unsigned* __restrict__ h0mask,
    float* __restrict__ out, float* __restrict__ last_h) {
    constexpr int ASZ = 128 * 64, BSZ = 64 * 64;
    __shared__ __bf16 As[2 * ASZ];
    __shared__ __bf16 Bs[2 * BSZ];
    const int NB = gridDim.x; // 1024
    const int aid = (blockIdx.x & 7) * (NB >> 3) + (blockIdx.x >> 3);
    const int bn = (aid & 31) * 64, bm = (aid >> 5) * 128;
    const int tid = threadIdx.x;
    const int lane = tid & 63, w = tid >> 6;
    const int wr = w >> 1, wc = w & 1;
    const int g = lane >> 4, lr = lane & 15;

    auto stage = [&](int buf, int k0) {
        #pragma unroll
        for (int i = 0; i < 4; ++i) {
            int D = i * 256 + tid;
            int row = D >> 3, pos = D & 7, c = pos ^ (row & 7);
            glds16(&tmp2[(size_t)(bm + row) * 128 + k0 + c * 8],
                   &As[buf * ASZ + (i * 256 + w * 64) * 8]);
        }
        #pragma unroll
        for (int i = 0; i < 2; ++i) {
            int D = i * 256 + tid;
            int row = D >> 3, pos = D & 7, c = pos ^ (row & 7);
            glds16(&WpairT[(size_t)(bn + row) * 128 + k0 + c * 8],
                   &Bs[buf * BSZ + (i * 256 + w * 64) * 8]);
        }
    };

    f32x4 acc[4][2] = {};
    const int x7 = lr & 7;
    const int ca[2] = {(g ^ x7) * 8, ((4 + g) ^ x7) * 8};
    const int arow0 = wr * 64 + lr, brow0 = wc * 32 + lr;
    stage(0, 0);
    __syncthreads();
    #pragma unroll
    for (int t = 0; t < 2; ++t) {
        if (t == 0) stage(1, 64);
        const __bf16* Ab = &As[t * ASZ];
        const __bf16* Bb = &Bs[t * BSZ];
        bf16x8 af[4][2], bfr[2][2];
        #pragma unroll
        for (int m = 0; m < 4; ++m)
            #pragma unroll
            for (int h = 0; h < 2; ++h)
                af[m][h] = *(const bf16x8*)&Ab[(arow0 + m * 16) * 64 + ca[h]];
        #pragma unroll
        for (int n = 0; n < 2; ++n)
            #pragma unroll
            for (int h = 0; h < 2; ++h)
                bfr[n][h] = *(const bf16x8*)&Bb[(brow0 + n * 16) * 64 + ca[h]];
        #pragma unroll
        for (int h = 0; h < 2; ++h)
            #pragma unroll
            for (int m = 0; m < 4; ++m)
                #pragma unroll
                for (int n = 0; n < 2; ++n)
                    acc[m][n] = __builtin_amdgcn_mfma_f32_16x16x32_bf16(
                        af[m][h], bfr[n][h], acc[m][n], 0, 0, 0);
        __syncthreads();
    }

    // in-kernel BC
    {
        int row = tid >> 3, pos = tid & 7, c = pos ^ (row & 7);
        #pragma unroll
        for (int t2 = 0; t2 < 2; ++t2)
            glds16(&WpairT[(size_t)(2048 + row) * 128 + t2 * 64 + c * 8],
                   &Bs[t2 * 2048 + w * 512]);
    }
    __syncthreads();
    f32x4 accB[2] = {}, accC[2] = {};
    #pragma unroll
    for (int t2 = 0; t2 < 2; ++t2) {
        const __bf16* Ab = &As[t2 * ASZ];
        #pragma unroll
        for (int h = 0; h < 2; ++h) {
            bf16x8 bB = *(const bf16x8*)&Bs[t2 * 2048 + lr * 64 + ca[h]];
            bf16x8 bC = *(const bf16x8*)&Bs[t2 * 2048 + (16 + lr) * 64 + ca[h]];
            #pragma unroll
            for (int m2 = 0; m2 < 2; ++m2) {
                bf16x8 a2 = *(const bf16x8*)&Ab[(w * 32 + m2 * 16 + lr) * 64 + ca[h]];
                accB[m2] = __builtin_amdgcn_mfma_f32_16x16x32_bf16(a2, bB, accB[m2], 0, 0, 0);
                accC[m2] = __builtin_amdgcn_mfma_f32_16x16x32_bf16(a2, bC, accC[m2], 0, 0, 0);
            }
        }
    }
    __syncthreads();
    float* sCB = (float*)As;
    __bf16* sBC = &Bs[BSZ];
    const float bB_ = bias_pair[2048 + lr], bC_ = bias_pair[2064 + lr];
    #pragma unroll
    for (int m2 = 0; m2 < 2; ++m2) {
        #pragma unroll
        for (int r = 0; r < 4; ++r) {
            int lrow = w * 32 + m2 * 16 + g * 4 + r;
            float vB = accB[m2][r] + bB_;
            float vC = accC[m2][r] + bC_;
            sBC[lrow * 32 + lr] = (__bf16)vB;
            sBC[lrow * 32 + 16 + lr] = (__bf16)vC;
            float p = vB * vC;
            #pragma unroll
            for (int m3 = 1; m3 < 16; m3 <<= 1) p += __shfl_xor(p, m3);
            if (lr == 0) sCB[lrow] = p;
        }
    }
    __syncthreads();

    const int d = ((bn + wc * 32) >> 1) + lr;
    const float bx_ = bias_pair[bn + wc * 32 + lr];
    const float bd_ = bias_pair[bn + wc * 32 + 16 + lr];
    const bool msk = (h0mask[d >> 5] >> (d & 31)) & 1u;
    #pragma unroll
    for (int m = 0; m < 4; ++m) {
        #pragma unroll
        for (int r = 0; r < 4; ++r) {
            const int lrow = wr * 64 + m * 16 + g * 4 + r;
            const int row = bm + lrow;
            const float xt = acc[m][0][r] + bx_;
            const float dr = acc[m][1][r] + bd_;
            const float e = __expf(-fabsf(dr));
            const float de = fmaxf(dr, 0.f) + __logf(1.f + e);
            const float xd = xt * de;
            float res = xd * sCB[lrow];
            const bool is_last = (row & (LSEQ - 1)) == (LSEQ - 1);
            if (msk) {
                float s = 0.f;
                #pragma unroll
                for (int n = 0; n < NDIM; ++n) {
                    float z = de * Amat[d * NDIM + n];
                    float c2 = (z > 0.f) ? z : __expf(z) - 1.f;
                    float da = __expf(-c2);
                    float h0v = h0[d * NDIM + n];
                    s += (float)sBC[lrow * 32 + 16 + n] * da * h0v;
                    if (is_last)
                        last_h[(((size_t)(row >> 11)) * DDIM + d) * NDIM + n] =
                            da * h0v + xd * (float)sBC[lrow * 32 + n];
                }
                res += s;
            } else if (is_last) {
                #pragma unroll
                for (int n = 0; n < NDIM; ++n)
                    last_h[(((size_t)(row >> 11)) * DDIM + d) * NDIM + n] =
                        xd * (float)sBC[lrow * 32 + n];
            }
            out[(size_t)row * DDIM + d] = res;
        }
    }
}

extern "C" void kernel_launch(void* const* d_in, const int* in_sizes, int n_in,
                              void* d_out, int out_size, void* d_ws, size_t ws_size,
                              hipStream_t stream) {
    const float* x   = (const float*)d_in[0];
    const float* W1  = (const float*)d_in[1];
    const float* b1  = (const float*)d_in[2];
    const float* W2  = (const float*)d_in[3];
    const float* b2  = (const float*)d_in[4];
    const float* W3  = (const float*)d_in[5];
    const float* b3  = (const float*)d_in[6];
    const float* Wl1 = (const float*)d_in[7];
    const float* bl1 = (const float*)d_in[8];
    const float* Wl2 = (const float*)d_in[9];
    const float* bl2 = (const float*)d_in[10];
    const float* Wf1 = (const float*)d_in[11];
    const float* bf1 = (const float*)d_in[12];
    const float* Wf2 = (const float*)d_in[13];
    const float* bf2 = (const float*)d_in[14];
    const float* h0  = (const float*)d_in[15];
    const float* Amat= (const float*)d_in[16];

    float* out    = (float*)d_out;
    float* last_h = (float*)d_out + (size_t)MROWS * DDIM;

    __bf16* wsb = (__bf16*)d_ws;
    size_t o = 0;
    auto alloc = [&](size_t n) { __bf16* p = wsb + o; o += n; return p; };
    __bf16* WaT    = alloc(256 * 1024);             // [Wl1 | Wf1_top]^T
    __bf16* Wf1bT  = alloc(128 * 1024);
    __bf16* Wl2T   = alloc(1024 * 128);
    __bf16* WbigT  = alloc((size_t)NPAD * 1024);    // [W1 | W2 | W3 | pad]^T
    __bf16* WpairT = alloc(2112 * 128);             // pairs 0..2047, BC 2048..2079
    __bf16* Wf2c   = alloc(128 * 1024);             // Wf2 bf16 row-major
    __bf16* tmp12  = alloc((size_t)MROWS * 256);    // [relu(x@Wl1+bl1) | x@Wf1_top]
    __bf16* tmp2   = alloc((size_t)MROWS * HDIM);
    float*  bias_pair = (float*)(wsb + o); o += 2 * 2112;
    unsigned* h0mask = (unsigned*)(wsb + o);

    // 1. pack (flat 1797 blocks)
    pack_all<<<dim3(1797), 256, 0, stream>>>(W1, W2, W3, Wl1, Wl2, Wf1, Wf2,
                                             bf2, h0,
                                             WbigT, WaT, Wf1bT, Wl2T, WpairT,
                                             Wf2c, bias_pair, h0mask);
    // 2. stage2: Gpre (68) + G1 (512) + bias fold (264)
    stage2_k<<<dim3(844), 256, 0, stream>>>(x, WaT, WbigT, Wf2c, bf2, b1, b2, b3,
                                            bl1, tmp12, WpairT, bias_pair);
    // 3. g23: fused G2+G3 (72 KB LDS, 2 blocks/CU) -> tmp2
    g23_k<<<dim3(256), 512, 0, stream>>>(tmp12, Wl2T, Wf1bT, bl2, bf1, tmp2);
    // 4. mm_pairs: fused [x_tr|delta] GEMM + BC + final epilogue -> out, last_h
    mm_pairs<<<dim3(32 * 32), 256, 0, stream>>>(tmp2, WpairT, bias_pair,
                                                Amat, h0, h0mask, out, last_h);
}

// Round 19
// 50.093 us; speedup vs baseline: 1.1632x; 1.0027x over previous
//
#include <hip/hip_runtime.h>
#include <cmath>

#define B_SZ 2
#define LSEQ 2048
#define DDIM 1024
#define NDIM 16
#define HDIM 128
#define MROWS (B_SZ * LSEQ)    // 4096
#define NBIG (DDIM + 2 * NDIM) // 1056
#define NPAD 1088              // NBIG padded to 64

typedef __bf16 bf16x8 __attribute__((ext_vector_type(8)));
typedef __bf16 bf16x4 __attribute__((ext_vector_type(4)));
typedef float f32x4 __attribute__((ext_vector_type(4)));

// async global->LDS, 16B/lane; LDS dest = wave-uniform base + lane*16
__device__ __forceinline__ void glds16(const __bf16* g, __bf16* l) {
    __builtin_amdgcn_global_load_lds(
        (const __attribute__((address_space(1))) unsigned int*)g,
        (__attribute__((address_space(3))) unsigned int*)l, 16, 0, 0);
}

// pair-layout row slots
__device__ __forceinline__ int slot_xt(int d) { return (d >> 4) * 32 + (d & 15); }
__device__ __forceinline__ int slot_de(int d) { return (d >> 4) * 32 + 16 + (d & 15); }

// ---------------------------------------------------------------------------
// Preprocessing (flat 1-D grid, 1797 blocks).
// ---------------------------------------------------------------------------
__device__ __forceinline__ void tcast_tile(const float* __restrict__ in,
                                           __bf16* __restrict__ out, int K, int N,
                                           int bx, int by, float (*t)[33]) {
    int tx = threadIdx.x & 31, ty = threadIdx.x >> 5;
    int n0 = bx * 32, k0 = by * 32;
    #pragma unroll
    for (int i = 0; i < 4; ++i) {
        int k = k0 + ty + i * 8, n = n0 + tx;
        t[ty + i * 8][tx] = (k < K && n < N) ? in[(size_t)k * N + n] : 0.f;
    }
    __syncthreads();
    #pragma unroll
    for (int i = 0; i < 4; ++i) {
        int n = n0 + ty + i * 8, k = k0 + tx;
        if (n < N && k < K) out[(size_t)n * K + k] = (__bf16)t[tx][ty + i * 8];
    }
}

// Wf2 [128][1024] -> WpairT xt slots (row slot_xt(n), ld 128)
__device__ __forceinline__ void tcast_pair_tile(const float* __restrict__ in,
                                                __bf16* __restrict__ out,
                                                int bx, int by, float (*t)[33]) {
    int tx = threadIdx.x & 31, ty = threadIdx.x >> 5;
    int n0 = bx * 32, k0 = by * 32;
    #pragma unroll
    for (int i = 0; i < 4; ++i) {
        int k = k0 + ty + i * 8, n = n0 + tx;
        t[ty + i * 8][tx] = in[(size_t)k * 1024 + n];
    }
    __syncthreads();
    #pragma unroll
    for (int i = 0; i < 4; ++i) {
        int n = n0 + ty + i * 8, k = k0 + tx;
        out[(size_t)slot_xt(n) * 128 + k] = (__bf16)t[tx][ty + i * 8];
    }
}

__global__ __launch_bounds__(256) void pack_all(
    const float* W1, const float* W2, const float* W3, const float* Wl1,
    const float* Wl2, const float* Wf1, const float* Wf2,
    const float* bf2, const float* h0,
    __bf16* WbigT, __bf16* WaT, __bf16* Wf1bT, __bf16* Wl2T, __bf16* WpairT,
    __bf16* Wf2c, float* bias_pair, unsigned* h0mask) {
    __shared__ float t[32][33];
    const int b = blockIdx.x;
    const int tid = threadIdx.x;
    if (b < 1024) {                       // W1 -> WbigT
        tcast_tile(W1, WbigT, 1024, 1024, b & 31, b >> 5, t);
    } else if (b < 1152) {                // Wl1 -> WaT
        int i = b - 1024; tcast_tile(Wl1, WaT, 1024, 128, i & 3, i >> 2, t);
    } else if (b < 1280) {                // Wf1 top -> WaT[128k..]
        int i = b - 1152; tcast_tile(Wf1, WaT + 128 * 1024, 1024, 128, i & 3, i >> 2, t);
    } else if (b < 1408) {                // Wf1 bottom -> Wf1bT
        int i = b - 1280;
        tcast_tile(Wf1 + (size_t)1024 * 128, Wf1bT, 1024, 128, i & 3, i >> 2, t);
    } else if (b < 1536) {                // Wl2 -> Wl2T
        int i = b - 1408; tcast_tile(Wl2, Wl2T, 128, 1024, i & 31, i >> 5, t);
    } else if (b < 1664) {                // Wf2 -> WpairT xt slots
        int i = b - 1536; tcast_pair_tile(Wf2, WpairT, i & 31, i >> 5, t);
    } else if (b < 1696) {                // W2 -> WbigT[1024..]
        int i = b - 1664; tcast_tile(W2, WbigT + (size_t)1024 * 1024, 1024, 16, 0, i, t);
    } else if (b < 1728) {                // W3 -> WbigT[1040..]
        int i = b - 1696; tcast_tile(W3, WbigT + (size_t)1040 * 1024, 1024, 16, 0, i, t);
    } else if (b < 1732) {                // xt bias scatter
        int i = (b - 1728) * 256 + tid;
        bias_pair[slot_xt(i)] = bf2[i];
    } else if (b < 1764) {                // zero WbigT pad rows
        int i = (b - 1732) * 256 + tid;
        #pragma unroll
        for (int r = 0; r < 4; ++r) {
            int e = i + r * 8192;
            if (e < 32 * 1024) WbigT[(size_t)1056 * 1024 + e] = (__bf16)0.f;
        }
    } else if (b < 1796) {                // Wf2 -> Wf2c row-major bf16
        int id = (b - 1764) * 256 + tid;
        #pragma unroll
        for (int j = 0; j < 4; ++j) {
            int e = id + j * 8192;
            float4 v = ((const float4*)Wf2)[e];
            bf16x4 o2 = {(__bf16)v.x, (__bf16)v.y, (__bf16)v.z, (__bf16)v.w};
            ((bf16x4*)Wf2c)[e] = o2;
        }
    } else {                              // h0 nonzero bitmask
        __shared__ unsigned sm[32];
        if (tid < 32) sm[tid] = 0u;
        __syncthreads();
        unsigned nib = 0;
        #pragma unroll
        for (int j = 0; j < 4; ++j) {
            int d = tid * 4 + j;
            const uint4* hu = (const uint4*)(h0 + d * NDIM);
            uint4 a0 = hu[0], a1 = hu[1], a2 = hu[2], a3 = hu[3];
            unsigned nz = a0.x | a0.y | a0.z | a0.w | a1.x | a1.y | a1.z | a1.w |
                          a2.x | a2.y | a2.z | a2.w | a3.x | a3.y | a3.z | a3.w;
            if (nz) nib |= (1u << j);
        }
        if (nib) atomicOr(&sm[(tid * 4) >> 5], nib << ((tid * 4) & 31));
        __syncthreads();
        if (tid < 32) h0mask[tid] = sm[tid];
    }
}

// ---------------------------------------------------------------------------
// Core BMxBN MFMA GEMM, templated BK/NBUF. XOR swizzle both sides.
// ACT: 1 relu(+prev), 2 fast-tanh, 4 split128-relu, 7 pair-scatter raw (Gpre)
// ---------------------------------------------------------------------------
template <int BM, int BN, int BK, int NBUF, int ACT, bool ADD_PREV, bool GUARDN, bool AF32>
__device__ __forceinline__ void gemm_core(
    const void* Av, int lda, const __bf16* __restrict__ Bt, int ldb, int Ntot,
    const float* __restrict__ bias, const __bf16* __restrict__ prev, int ldp,
    __bf16* __restrict__ C, int ldc, int K, int bm, int bn,
    __bf16* As, __bf16* Bs) {
    constexpr int WM = BM / 2, WN = BN / 2, FM = WM / 16, FN = WN / 16;
    constexpr int ASZ = BM * BK, BSZ = BN * BK;
    constexpr int CPR = BK / 8;
    constexpr int NH = BK / 32;
    const int tid = threadIdx.x;
    const int lane = tid & 63, w = tid >> 6;
    const int wr = w >> 1, wc = w & 1;
    const int g = lane >> 4, lr = lane & 15;
    const __bf16* A16 = (const __bf16*)Av;
    const float* A32 = (const float*)Av;

    auto stage = [&](int buf, int k0) {
        #pragma unroll
        for (int i = 0; i < BM * BK / 2048; ++i) {
            int D = i * 256 + tid;
            int row = D / CPR, pos = D % CPR, c = pos ^ (row & 7);
            if constexpr (AF32) {
                const float* s = &A32[(size_t)(bm + row) * lda + k0 + c * 8];
                float4 v0 = *(const float4*)s;
                float4 v1 = *(const float4*)(s + 4);
                bf16x8 pk = {(__bf16)v0.x, (__bf16)v0.y, (__bf16)v0.z, (__bf16)v0.w,
                             (__bf16)v1.x, (__bf16)v1.y, (__bf16)v1.z, (__bf16)v1.w};
                *(bf16x8*)&As[buf * ASZ + row * BK + pos * 8] = pk;
            } else {
                glds16(&A16[(size_t)(bm + row) * lda + k0 + c * 8],
                       &As[buf * ASZ + (i * 256 + w * 64) * 8]);
            }
        }
        #pragma unroll
        for (int i = 0; i < BN * BK / 2048; ++i) {
            int D = i * 256 + tid;
            int row = D / CPR, pos = D % CPR, c = pos ^ (row & 7);
            glds16(&Bt[(size_t)(bn + row) * ldb + k0 + c * 8],
                   &Bs[buf * BSZ + (i * 256 + w * 64) * 8]);
        }
    };

    f32x4 acc[FM][FN] = {};
    const int x7 = lr & 7;
    int ca[NH];
    #pragma unroll
    for (int h = 0; h < NH; ++h) ca[h] = ((h * 4 + g) ^ x7) * 8;
    const int arow0 = wr * WM + lr;
    const int brow0 = wc * WN + lr;

    const int nt = K / BK;
    stage(0, 0);
    __syncthreads();
    for (int t = 0; t < nt; ++t) {
        if (NBUF == 2 && t + 1 < nt) stage((t + 1) & 1, (t + 1) * BK);
        const __bf16* Ab = &As[(NBUF == 2 ? (t & 1) : 0) * ASZ];
        const __bf16* Bb = &Bs[(NBUF == 2 ? (t & 1) : 0) * BSZ];
        bf16x8 af[FM][NH], bfr[FN][NH];
        #pragma unroll
        for (int m = 0; m < FM; ++m)
            #pragma unroll
            for (int h = 0; h < NH; ++h)
                af[m][h] = *(const bf16x8*)&Ab[(arow0 + m * 16) * BK + ca[h]];
        #pragma unroll
        for (int n = 0; n < FN; ++n)
            #pragma unroll
            for (int h = 0; h < NH; ++h)
                bfr[n][h] = *(const bf16x8*)&Bb[(brow0 + n * 16) * BK + ca[h]];
        #pragma unroll
        for (int h = 0; h < NH; ++h)
            #pragma unroll
            for (int m = 0; m < FM; ++m)
                #pragma unroll
                for (int n = 0; n < FN; ++n)
                    acc[m][n] = __builtin_amdgcn_mfma_f32_16x16x32_bf16(
                        af[m][h], bfr[n][h], acc[m][n], 0, 0, 0);
        __syncthreads();
    }

    #pragma unroll
    for (int m = 0; m < FM; ++m) {
        #pragma unroll
        for (int n = 0; n < FN; ++n) {
            #pragma unroll
            for (int r = 0; r < 4; ++r) {
                int grow = bm + wr * WM + m * 16 + g * 4 + r;
                int gcol = bn + wc * WN + n * 16 + lr;
                if (!GUARDN || gcol < Ntot) {
                    float v = acc[m][n][r];
                    int orow = grow;
                    if (ACT == 1) {
                        v += bias[gcol];
                        if (ADD_PREV) v += (float)prev[(size_t)grow * ldp + gcol];
                        v = fmaxf(v, 0.f);
                    } else if (ACT == 2) {
                        v += bias[gcol];
                        float e = __expf(2.f * v);
                        v = 1.f - 2.f * __builtin_amdgcn_rcpf(e + 1.f);
                    } else if (ACT == 4) {
                        if (gcol < HDIM) v = fmaxf(v + bias[gcol], 0.f);
                    } else if (ACT == 7) { // Gpre pair-scatter, raw
                        orow = (grow < 1024) ? slot_de(grow) : 2048 + (grow - 1024);
                    }
                    C[(size_t)orow * ldc + gcol] = (__bf16)v;
                }
            }
        }
    }
}

// ---------------------------------------------------------------------------
// stage2: [0,68) Gpre FIRST; [68,580) G1 (x fp32 reg-staged, BK=128);
// [580,844) bias fold.
// ---------------------------------------------------------------------------
__global__ __launch_bounds__(256) void stage2_k(
    const float* __restrict__ x, const __bf16* __restrict__ WaT,
    const __bf16* __restrict__ WbigT, const __bf16* __restrict__ Wf2c,
    const float* __restrict__ bf2, const float* __restrict__ b1,
    const float* __restrict__ b2, const float* __restrict__ b3,
    const float* __restrict__ bl1,
    __bf16* __restrict__ tmp12, __bf16* __restrict__ WpairT,
    float* __restrict__ bias_pair) {
    __shared__ __bf16 As[8192];
    __shared__ __bf16 Bs[16384];
    const int b = blockIdx.x;
    if (b < 68) {
        // Gpre: Wcomb cols scattered into WpairT delta/BC slots  M=1088 N=128 K=1024
        const int bm = (b >> 1) * 32, bn = (b & 1) * 64;
        gemm_core<32, 64, 128, 2, 7, false, false, false>(
            WbigT, 1024, Wf2c, 1024, 128, nullptr, nullptr, 0,
            WpairT, 128, 1024, bm, bn, As, Bs);
    } else if (b < 580) {
        // G1: tmp12 = [relu(x@Wl1+bl1) | x@Wf1_top]  M=4096 N=256 K=1024
        const int lb = b - 68;
        const int aid = (lb & 7) * 64 + (lb >> 3);
        const int bn = (aid & 3) * 64, bm = (aid >> 2) * 32;
        gemm_core<32, 64, 128, 2, 4, false, false, true>(
            x, DDIM, WaT, 1024, 256, bl1, nullptr, 0, tmp12, 256, 1024, bm, bn, As, Bs);
    } else {
        // bias fold: fold(n) = ball[n] + sum_d bf2[d]*Wall[d][n] -> pair/BC slots
        const int n = (b - 580) * 4 + (threadIdx.x >> 6);
        const int lane = threadIdx.x & 63;
        const __bf16* wr = WbigT + (size_t)n * 1024 + lane * 16;
        float s = 0.f;
        #pragma unroll
        for (int i = 0; i < 2; ++i) {
            bf16x8 wv = *(const bf16x8*)&wr[i * 8];
            float4 f0 = *(const float4*)&bf2[lane * 16 + i * 8];
            float4 f1 = *(const float4*)&bf2[lane * 16 + i * 8 + 4];
            s += (float)wv[0] * f0.x + (float)wv[1] * f0.y + (float)wv[2] * f0.z +
                 (float)wv[3] * f0.w + (float)wv[4] * f1.x + (float)wv[5] * f1.y +
                 (float)wv[6] * f1.z + (float)wv[7] * f1.w;
        }
        #pragma unroll
        for (int off = 32; off; off >>= 1) s += __shfl_down(s, off);
        if (lane == 0) {
            float base = (n < DDIM) ? b1[n]
                       : (n < DDIM + NDIM) ? b2[n - DDIM] : b3[n - DDIM - NDIM];
            int sl = (n < DDIM) ? slot_de(n) : 2048 + (n - DDIM);
            bias_pair[sl] = base + s;
        }
    }
}

// ---------------------------------------------------------------------------
// g23_k: fused G2+G3, SINGLE-buffered B tiles -> 72 KB LDS -> 2 blocks/CU
// (TLP covers staging latency; barriers drain vmcnt anyway so double-buffer
// bought nothing within a block — m114 mechanism).
// Issue discipline: B2(t+1) after sync2 (drained by next sync1, used phase2);
// B1(t+1) after sync1 (drained at sync2, used next phase1).
// ---------------------------------------------------------------------------
__global__ __launch_bounds__(512) void g23_k(
    const __bf16* __restrict__ tmp12, const __bf16* __restrict__ Wl2T,
    const __bf16* __restrict__ Wf1bT, const float* __restrict__ bl2,
    const float* __restrict__ bf1, __bf16* __restrict__ tmp2) {
    __shared__ __bf16 T1[2048];       // t1 16x128 (swizzled chunks)
    __shared__ __bf16 LS[2048];       // lifted chunk 16x128 (swizzled)
    __shared__ __bf16 B1[16384];      // Wl2T rows [kc..kc+128) x 128 (single)
    __shared__ __bf16 B2[16384];      // Wf1bT rows [0,128) x [kc..kc+128) (single)
    const int tid = threadIdx.x;
    const int lane = tid & 63, w = tid >> 6;
    const int g = lane >> 4, lr = lane & 15;
    const int x7 = lr & 7;
    const int bm = blockIdx.x * 16;

    if (tid < 256) {
        int row = tid >> 4, pos = tid & 15, c = pos ^ (row & 7);
        glds16(&tmp12[(size_t)(bm + row) * 256 + c * 8], &T1[w * 512]);
    }
    auto stageB1 = [&](int kc) {
        #pragma unroll
        for (int i = 0; i < 4; ++i) {
            int D = i * 512 + tid;
            int row = D >> 4, pos = D & 15, c = pos ^ (row & 7);
            glds16(&Wl2T[(size_t)(kc + row) * 128 + c * 8],
                   &B1[(i * 512 + w * 64) * 8]);
        }
    };
    auto stageB2 = [&](int kc) {
        #pragma unroll
        for (int i = 0; i < 4; ++i) {
            int D = i * 512 + tid;
            int row = D >> 4, pos = D & 15, c = pos ^ (row & 7);
            glds16(&Wf1bT[(size_t)row * 1024 + kc + c * 8],
                   &B2[(i * 512 + w * 64) * 8]);
        }
    };

    int ca[4];
    #pragma unroll
    for (int h = 0; h < 4; ++h) ca[h] = ((h * 4 + g) ^ x7) * 8;
    const int col = w * 16 + lr;      // this thread's output column (0..127)
    const int brow = col * 128;

    stageB1(0);
    stageB2(0);
    __syncthreads();
    bf16x8 a1[4];
    #pragma unroll
    for (int h = 0; h < 4; ++h) a1[h] = *(const bf16x8*)&T1[lr * 128 + ca[h]];

    f32x4 acc2 = {};
    for (int t = 0; t < 8; ++t) {
        // phase1: lifted_c[:, col] from B1 (current)
        f32x4 acc1 = {};
        #pragma unroll
        for (int h = 0; h < 4; ++h) {
            bf16x8 bf = *(const bf16x8*)&B1[brow + ca[h]];
            acc1 = __builtin_amdgcn_mfma_f32_16x16x32_bf16(a1[h], bf, acc1, 0, 0, 0);
        }
        const float bl = bl2[t * 128 + col];
        const int chunk = col >> 3, cin = col & 7;
        #pragma unroll
        for (int r = 0; r < 4; ++r) {
            float v = acc1[r] + bl;
            float e = __expf(2.f * v);
            v = 1.f - 2.f * __builtin_amdgcn_rcpf(e + 1.f);  // tanh
            int row = g * 4 + r;
            LS[row * 128 + ((chunk ^ (row & 7)) << 3) + cin] = (__bf16)v;
        }
        __syncthreads();                 // sync1: LS visible; B1/B2 reads done
        if (t + 1 < 8) stageB1((t + 1) * 128);  // in flight across phase2
        // phase2: acc2 += lifted_c @ Wf1b-chunk from B2 (current)
        #pragma unroll
        for (int h = 0; h < 4; ++h) {
            bf16x8 a2 = *(const bf16x8*)&LS[lr * 128 + ca[h]];
            bf16x8 bf = *(const bf16x8*)&B2[brow + ca[h]];
            acc2 = __builtin_amdgcn_mfma_f32_16x16x32_bf16(a2, bf, acc2, 0, 0, 0);
        }
        __syncthreads();                 // sync2: drains B1(t+1); B2/LS free
        if (t + 1 < 8) stageB2((t + 1) * 128);  // drained by next sync1
    }

    const float bfv = bf1[col];
    #pragma unroll
    for (int r = 0; r < 4; ++r) {
        const int row = g * 4 + r;
        float v = acc2[r] + bfv + (float)tmp12[(size_t)(bm + row) * 256 + 128 + col];
        v = fmaxf(v, 0.f);
        tmp2[(size_t)(bm + row) * 128 + col] = (__bf16)v;
    }
}

// ---------------------------------------------------------------------------
// mm_pairs: [xt|de] pair GEMM + in-kernel BC (Bm/Cm/cb) + final epilogue.
// M=4096 N=2048 K=128. BM=128 BN=64, 1024 blocks, LDS 48 KB.
// ---------------------------------------------------------------------------
__global__ __launch_bounds__(256) void mm_pairs(
    const __bf16* __restrict__ tmp2, const __bf16* __restrict__ WpairT,
    const float* __restrict__ bias_pair,
    const float* __restrict__ Amat, const float* __restrict__ h0,
    const unsigned* __restrict__ h0mask,
    float* __restrict__ out, float* __restrict__ last_h) {
    constexpr int ASZ = 128 * 64, BSZ = 64 * 64;
    __shared__ __bf16 As[2 * ASZ];
    __shared__ __bf16 Bs[2 * BSZ];
    const int NB = gridDim.x; // 1024
    const int aid = (blockIdx.x & 7) * (NB >> 3) + (blockIdx.x >> 3);
    const int bn = (aid & 31) * 64, bm = (aid >> 5) * 128;
    const int tid = threadIdx.x;
    const int lane = tid & 63, w = tid >> 6;
    const int wr = w >> 1, wc = w & 1;
    const int g = lane >> 4, lr = lane & 15;

    auto stage = [&](int buf, int k0) {
        #pragma unroll
        for (int i = 0; i < 4; ++i) {
            int D = i * 256 + tid;
            int row = D >> 3, pos = D & 7, c = pos ^ (row & 7);
            glds16(&tmp2[(size_t)(bm + row) * 128 + k0 + c * 8],
                   &As[buf * ASZ + (i * 256 + w * 64) * 8]);
        }
        #pragma unroll
        for (int i = 0; i < 2; ++i) {
            int D = i * 256 + tid;
            int row = D >> 3, pos = D & 7, c = pos ^ (row & 7);
            glds16(&WpairT[(size_t)(bn + row) * 128 + k0 + c * 8],
                   &Bs[buf * BSZ + (i * 256 + w * 64) * 8]);
        }
    };

    f32x4 acc[4][2] = {};
    const int x7 = lr & 7;
    const int ca[2] = {(g ^ x7) * 8, ((4 + g) ^ x7) * 8};
    const int arow0 = wr * 64 + lr, brow0 = wc * 32 + lr;
    stage(0, 0);
    __syncthreads();
    #pragma unroll
    for (int t = 0; t < 2; ++t) {
        if (t == 0) stage(1, 64);
        const __bf16* Ab = &As[t * ASZ];
        const __bf16* Bb = &Bs[t * BSZ];
        bf16x8 af[4][2], bfr[2][2];
        #pragma unroll
        for (int m = 0; m < 4; ++m)
            #pragma unroll
            for (int h = 0; h < 2; ++h)
                af[m][h] = *(const bf16x8*)&Ab[(arow0 + m * 16) * 64 + ca[h]];
        #pragma unroll
        for (int n = 0; n < 2; ++n)
            #pragma unroll
            for (int h = 0; h < 2; ++h)
                bfr[n][h] = *(const bf16x8*)&Bb[(brow0 + n * 16) * 64 + ca[h]];
        #pragma unroll
        for (int h = 0; h < 2; ++h)
            #pragma unroll
            for (int m = 0; m < 4; ++m)
                #pragma unroll
                for (int n = 0; n < 2; ++n)
                    acc[m][n] = __builtin_amdgcn_mfma_f32_16x16x32_bf16(
                        af[m][h], bfr[n][h], acc[m][n], 0, 0, 0);
        __syncthreads();
    }

    // in-kernel BC
    {
        int row = tid >> 3, pos = tid & 7, c = pos ^ (row & 7);
        #pragma unroll
        for (int t2 = 0; t2 < 2; ++t2)
            glds16(&WpairT[(size_t)(2048 + row) * 128 + t2 * 64 + c * 8],
                   &Bs[t2 * 2048 + w * 512]);
    }
    __syncthreads();
    f32x4 accB[2] = {}, accC[2] = {};
    #pragma unroll
    for (int t2 = 0; t2 < 2; ++t2) {
        const __bf16* Ab = &As[t2 * ASZ];
        #pragma unroll
        for (int h = 0; h < 2; ++h) {
            bf16x8 bB = *(const bf16x8*)&Bs[t2 * 2048 + lr * 64 + ca[h]];
            bf16x8 bC = *(const bf16x8*)&Bs[t2 * 2048 + (16 + lr) * 64 + ca[h]];
            #pragma unroll
            for (int m2 = 0; m2 < 2; ++m2) {
                bf16x8 a2 = *(const bf16x8*)&Ab[(w * 32 + m2 * 16 + lr) * 64 + ca[h]];
                accB[m2] = __builtin_amdgcn_mfma_f32_16x16x32_bf16(a2, bB, accB[m2], 0, 0, 0);
                accC[m2] = __builtin_amdgcn_mfma_f32_16x16x32_bf16(a2, bC, accC[m2], 0, 0, 0);
            }
        }
    }
    __syncthreads();
    float* sCB = (float*)As;
    __bf16* sBC = &Bs[BSZ];
    const float bB_ = bias_pair[2048 + lr], bC_ = bias_pair[2064 + lr];
    #pragma unroll
    for (int m2 = 0; m2 < 2; ++m2) {
        #pragma unroll
        for (int r = 0; r < 4; ++r) {
            int lrow = w * 32 + m2 * 16 + g * 4 + r;
            float vB = accB[m2][r] + bB_;
            float vC = accC[m2][r] + bC_;
            sBC[lrow * 32 + lr] = (__bf16)vB;
            sBC[lrow * 32 + 16 + lr] = (__bf16)vC;
            float p = vB * vC;
            #pragma unroll
            for (int m3 = 1; m3 < 16; m3 <<= 1) p += __shfl_xor(p, m3);
            if (lr == 0) sCB[lrow] = p;
        }
    }
    __syncthreads();

    const int d = ((bn + wc * 32) >> 1) + lr;
    const float bx_ = bias_pair[bn + wc * 32 + lr];
    const float bd_ = bias_pair[bn + wc * 32 + 16 + lr];
    const bool msk = (h0mask[d >> 5] >> (d & 31)) & 1u;
    #pragma unroll
    for (int m = 0; m < 4; ++m) {
        #pragma unroll
        for (int r = 0; r < 4; ++r) {
            const int lrow = wr * 64 + m * 16 + g * 4 + r;
            const int row = bm + lrow;
            const float xt = acc[m][0][r] + bx_;
            const float dr = acc[m][1][r] + bd_;
            const float e = __expf(-fabsf(dr));
            const float de = fmaxf(dr, 0.f) + __logf(1.f + e);
            const float xd = xt * de;
            float res = xd * sCB[lrow];
            const bool is_last = (row & (LSEQ - 1)) == (LSEQ - 1);
            if (msk) {
                float s = 0.f;
                #pragma unroll
                for (int n = 0; n < NDIM; ++n) {
                    float z = de * Amat[d * NDIM + n];
                    float c2 = (z > 0.f) ? z : __expf(z) - 1.f;
                    float da = __expf(-c2);
                    float h0v = h0[d * NDIM + n];
                    s += (float)sBC[lrow * 32 + 16 + n] * da * h0v;
                    if (is_last)
                        last_h[(((size_t)(row >> 11)) * DDIM + d) * NDIM + n] =
                            da * h0v + xd * (float)sBC[lrow * 32 + n];
                }
                res += s;
            } else if (is_last) {
                #pragma unroll
                for (int n = 0; n < NDIM; ++n)
                    last_h[(((size_t)(row >> 11)) * DDIM + d) * NDIM + n] =
                        xd * (float)sBC[lrow * 32 + n];
            }
            out[(size_t)row * DDIM + d] = res;
        }
    }
}

extern "C" void kernel_launch(void* const* d_in, const int* in_sizes, int n_in,
                              void* d_out, int out_size, void* d_ws, size_t ws_size,
                              hipStream_t stream) {
    const float* x   = (const float*)d_in[0];
    const float* W1  = (const float*)d_in[1];
    const float* b1  = (const float*)d_in[2];
    const float* W2  = (const float*)d_in[3];
    const float* b2  = (const float*)d_in[4];
    const float* W3  = (const float*)d_in[5];
    const float* b3  = (const float*)d_in[6];
    const float* Wl1 = (const float*)d_in[7];
    const float* bl1 = (const float*)d_in[8];
    const float* Wl2 = (const float*)d_in[9];
    const float* bl2 = (const float*)d_in[10];
    const float* Wf1 = (const float*)d_in[11];
    const float* bf1 = (const float*)d_in[12];
    const float* Wf2 = (const float*)d_in[13];
    const float* bf2 = (const float*)d_in[14];
    const float* h0  = (const float*)d_in[15];
    const float* Amat= (const float*)d_in[16];

    float* out    = (float*)d_out;
    float* last_h = (float*)d_out + (size_t)MROWS * DDIM;

    __bf16* wsb = (__bf16*)d_ws;
    size_t o = 0;
    auto alloc = [&](size_t n) { __bf16* p = wsb + o; o += n; return p; };
    __bf16* WaT    = alloc(256 * 1024);             // [Wl1 | Wf1_top]^T
    __bf16* Wf1bT  = alloc(128 * 1024);
    __bf16* Wl2T   = alloc(1024 * 128);
    __bf16* WbigT  = alloc((size_t)NPAD * 1024);    // [W1 | W2 | W3 | pad]^T
    __bf16* WpairT = alloc(2112 * 128);             // pairs 0..2047, BC 2048..2079
    __bf16* Wf2c   = alloc(128 * 1024);             // Wf2 bf16 row-major
    __bf16* tmp12  = alloc((size_t)MROWS * 256);    // [relu(x@Wl1+bl1) | x@Wf1_top]
    __bf16* tmp2   = alloc((size_t)MROWS * HDIM);
    float*  bias_pair = (float*)(wsb + o); o += 2 * 2112;
    unsigned* h0mask = (unsigned*)(wsb + o);

    // 1. pack (flat 1797 blocks)
    pack_all<<<dim3(1797), 256, 0, stream>>>(W1, W2, W3, Wl1, Wl2, Wf1, Wf2,
                                             bf2, h0,
                                             WbigT, WaT, Wf1bT, Wl2T, WpairT,
                                             Wf2c, bias_pair, h0mask);
    // 2. stage2: Gpre (68) + G1 (512) + bias fold (264)
    stage2_k<<<dim3(844), 256, 0, stream>>>(x, WaT, WbigT, Wf2c, bf2, b1, b2, b3,
                                            bl1, tmp12, WpairT, bias_pair);
    // 3. g23: fused G2+G3 (72 KB LDS, 2 blocks/CU) -> tmp2
    g23_k<<<dim3(256), 512, 0, stream>>>(tmp12, Wl2T, Wf1bT, bl2, bf1, tmp2);
    // 4. mm_pairs: fused [x_tr|delta] GEMM + BC + final epilogue -> out, last_h
    mm_pairs<<<dim3(32 * 32), 256, 0, stream>>>(tmp2, WpairT, bias_pair,
                                                Amat, h0, h0mask, out, last_h);
}

// Round 20
// 49.085 us; speedup vs baseline: 1.1871x; 1.0206x over previous
//
#include <hip/hip_runtime.h>
#include <cmath>

#define B_SZ 2
#define LSEQ 2048
#define DDIM 1024
#define NDIM 16
#define HDIM 128
#define MROWS (B_SZ * LSEQ)    // 4096
#define NBIG (DDIM + 2 * NDIM) // 1056
#define NPAD 1088              // NBIG padded to 64

typedef __bf16 bf16x8 __attribute__((ext_vector_type(8)));
typedef __bf16 bf16x4 __attribute__((ext_vector_type(4)));
typedef float f32x4 __attribute__((ext_vector_type(4)));

// async global->LDS, 16B/lane; LDS dest = wave-uniform base + lane*16
__device__ __forceinline__ void glds16(const __bf16* g, __bf16* l) {
    __builtin_amdgcn_global_load_lds(
        (const __attribute__((address_space(1))) unsigned int*)g,
        (__attribute__((address_space(3))) unsigned int*)l, 16, 0, 0);
}

// pair-layout row slots
__device__ __forceinline__ int slot_xt(int d) { return (d >> 4) * 32 + (d & 15); }
__device__ __forceinline__ int slot_de(int d) { return (d >> 4) * 32 + 16 + (d & 15); }

// ---------------------------------------------------------------------------
// Preprocessing (flat 1-D grid, 1797 blocks).
// ---------------------------------------------------------------------------
__device__ __forceinline__ void tcast_tile(const float* __restrict__ in,
                                           __bf16* __restrict__ out, int K, int N,
                                           int bx, int by, float (*t)[33]) {
    int tx = threadIdx.x & 31, ty = threadIdx.x >> 5;
    int n0 = bx * 32, k0 = by * 32;
    #pragma unroll
    for (int i = 0; i < 4; ++i) {
        int k = k0 + ty + i * 8, n = n0 + tx;
        t[ty + i * 8][tx] = (k < K && n < N) ? in[(size_t)k * N + n] : 0.f;
    }
    __syncthreads();
    #pragma unroll
    for (int i = 0; i < 4; ++i) {
        int n = n0 + ty + i * 8, k = k0 + tx;
        if (n < N && k < K) out[(size_t)n * K + k] = (__bf16)t[tx][ty + i * 8];
    }
}

// Wf2 [128][1024] -> WpairT xt slots (row slot_xt(n), ld 128)
__device__ __forceinline__ void tcast_pair_tile(const float* __restrict__ in,
                                                __bf16* __restrict__ out,
                                                int bx, int by, float (*t)[33]) {
    int tx = threadIdx.x & 31, ty = threadIdx.x >> 5;
    int n0 = bx * 32, k0 = by * 32;
    #pragma unroll
    for (int i = 0; i < 4; ++i) {
        int k = k0 + ty + i * 8, n = n0 + tx;
        t[ty + i * 8][tx] = in[(size_t)k * 1024 + n];
    }
    __syncthreads();
    #pragma unroll
    for (int i = 0; i < 4; ++i) {
        int n = n0 + ty + i * 8, k = k0 + tx;
        out[(size_t)slot_xt(n) * 128 + k] = (__bf16)t[tx][ty + i * 8];
    }
}

__global__ __launch_bounds__(256) void pack_all(
    const float* W1, const float* W2, const float* W3, const float* Wl1,
    const float* Wl2, const float* Wf1, const float* Wf2,
    const float* bf2, const float* h0,
    __bf16* WbigT, __bf16* WaT, __bf16* Wf1bT, __bf16* Wl2T, __bf16* WpairT,
    __bf16* Wf2c, float* bias_pair, unsigned* h0mask) {
    __shared__ float t[32][33];
    const int b = blockIdx.x;
    const int tid = threadIdx.x;
    if (b < 1024) {                       // W1 -> WbigT
        tcast_tile(W1, WbigT, 1024, 1024, b & 31, b >> 5, t);
    } else if (b < 1152) {                // Wl1 -> WaT
        int i = b - 1024; tcast_tile(Wl1, WaT, 1024, 128, i & 3, i >> 2, t);
    } else if (b < 1280) {                // Wf1 top -> WaT[128k..]
        int i = b - 1152; tcast_tile(Wf1, WaT + 128 * 1024, 1024, 128, i & 3, i >> 2, t);
    } else if (b < 1408) {                // Wf1 bottom -> Wf1bT
        int i = b - 1280;
        tcast_tile(Wf1 + (size_t)1024 * 128, Wf1bT, 1024, 128, i & 3, i >> 2, t);
    } else if (b < 1536) {                // Wl2 -> Wl2T
        int i = b - 1408; tcast_tile(Wl2, Wl2T, 128, 1024, i & 31, i >> 5, t);
    } else if (b < 1664) {                // Wf2 -> WpairT xt slots
        int i = b - 1536; tcast_pair_tile(Wf2, WpairT, i & 31, i >> 5, t);
    } else if (b < 1696) {                // W2 -> WbigT[1024..]
        int i = b - 1664; tcast_tile(W2, WbigT + (size_t)1024 * 1024, 1024, 16, 0, i, t);
    } else if (b < 1728) {                // W3 -> WbigT[1040..]
        int i = b - 1696; tcast_tile(W3, WbigT + (size_t)1040 * 1024, 1024, 16, 0, i, t);
    } else if (b < 1732) {                // xt bias scatter
        int i = (b - 1728) * 256 + tid;
        bias_pair[slot_xt(i)] = bf2[i];
    } else if (b < 1764) {                // zero WbigT pad rows
        int i = (b - 1732) * 256 + tid;
        #pragma unroll
        for (int r = 0; r < 4; ++r) {
            int e = i + r * 8192;
            if (e < 32 * 1024) WbigT[(size_t)1056 * 1024 + e] = (__bf16)0.f;
        }
    } else if (b < 1796) {                // Wf2 -> Wf2c row-major bf16
        int id = (b - 1764) * 256 + tid;
        #pragma unroll
        for (int j = 0; j < 4; ++j) {
            int e = id + j * 8192;
            float4 v = ((const float4*)Wf2)[e];
            bf16x4 o2 = {(__bf16)v.x, (__bf16)v.y, (__bf16)v.z, (__bf16)v.w};
            ((bf16x4*)Wf2c)[e] = o2;
        }
    } else {                              // h0 nonzero bitmask
        __shared__ unsigned sm[32];
        if (tid < 32) sm[tid] = 0u;
        __syncthreads();
        unsigned nib = 0;
        #pragma unroll
        for (int j = 0; j < 4; ++j) {
            int d = tid * 4 + j;
            const uint4* hu = (const uint4*)(h0 + d * NDIM);
            uint4 a0 = hu[0], a1 = hu[1], a2 = hu[2], a3 = hu[3];
            unsigned nz = a0.x | a0.y | a0.z | a0.w | a1.x | a1.y | a1.z | a1.w |
                          a2.x | a2.y | a2.z | a2.w | a3.x | a3.y | a3.z | a3.w;
            if (nz) nib |= (1u << j);
        }
        if (nib) atomicOr(&sm[(tid * 4) >> 5], nib << ((tid * 4) & 31));
        __syncthreads();
        if (tid < 32) h0mask[tid] = sm[tid];
    }
}

// ---------------------------------------------------------------------------
// Core BMxBN MFMA GEMM, templated BK/NBUF; tid passed so a 512-thread block
// can run two independent 256-thread halves (identical barrier counts).
// XOR swizzle both sides. ACT: 4 split128-relu, 7 pair-scatter raw (Gpre)
// ---------------------------------------------------------------------------
template <int BM, int BN, int BK, int NBUF, int ACT, bool GUARDN, bool AF32>
__device__ __forceinline__ void gemm_core(
    const void* Av, int lda, const __bf16* __restrict__ Bt, int ldb, int Ntot,
    const float* __restrict__ bias,
    __bf16* __restrict__ C, int ldc, int K, int bm, int bn,
    __bf16* As, __bf16* Bs, int tid) {
    constexpr int WM = BM / 2, WN = BN / 2, FM = WM / 16, FN = WN / 16;
    constexpr int ASZ = BM * BK, BSZ = BN * BK;
    constexpr int CPR = BK / 8;
    constexpr int NH = BK / 32;
    const int lane = tid & 63, w = tid >> 6;
    const int wr = w >> 1, wc = w & 1;
    const int g = lane >> 4, lr = lane & 15;
    const __bf16* A16 = (const __bf16*)Av;
    const float* A32 = (const float*)Av;

    auto stage = [&](int buf, int k0) {
        #pragma unroll
        for (int i = 0; i < BM * BK / 2048; ++i) {
            int D = i * 256 + tid;
            int row = D / CPR, pos = D % CPR, c = pos ^ (row & 7);
            if constexpr (AF32) {
                const float* s = &A32[(size_t)(bm + row) * lda + k0 + c * 8];
                float4 v0 = *(const float4*)s;
                float4 v1 = *(const float4*)(s + 4);
                bf16x8 pk = {(__bf16)v0.x, (__bf16)v0.y, (__bf16)v0.z, (__bf16)v0.w,
                             (__bf16)v1.x, (__bf16)v1.y, (__bf16)v1.z, (__bf16)v1.w};
                *(bf16x8*)&As[buf * ASZ + row * BK + pos * 8] = pk;
            } else {
                glds16(&A16[(size_t)(bm + row) * lda + k0 + c * 8],
                       &As[buf * ASZ + (i * 256 + w * 64) * 8]);
            }
        }
        #pragma unroll
        for (int i = 0; i < BN * BK / 2048; ++i) {
            int D = i * 256 + tid;
            int row = D / CPR, pos = D % CPR, c = pos ^ (row & 7);
            glds16(&Bt[(size_t)(bn + row) * ldb + k0 + c * 8],
                   &Bs[buf * BSZ + (i * 256 + w * 64) * 8]);
        }
    };

    f32x4 acc[FM][FN] = {};
    const int x7 = lr & 7;
    int ca[NH];
    #pragma unroll
    for (int h = 0; h < NH; ++h) ca[h] = ((h * 4 + g) ^ x7) * 8;
    const int arow0 = wr * WM + lr;
    const int brow0 = wc * WN + lr;

    const int nt = K / BK;
    stage(0, 0);
    __syncthreads();
    for (int t = 0; t < nt; ++t) {
        if (NBUF == 2 && t + 1 < nt) stage((t + 1) & 1, (t + 1) * BK);
        const __bf16* Ab = &As[(NBUF == 2 ? (t & 1) : 0) * ASZ];
        const __bf16* Bb = &Bs[(NBUF == 2 ? (t & 1) : 0) * BSZ];
        bf16x8 af[FM][NH], bfr[FN][NH];
        #pragma unroll
        for (int m = 0; m < FM; ++m)
            #pragma unroll
            for (int h = 0; h < NH; ++h)
                af[m][h] = *(const bf16x8*)&Ab[(arow0 + m * 16) * BK + ca[h]];
        #pragma unroll
        for (int n = 0; n < FN; ++n)
            #pragma unroll
            for (int h = 0; h < NH; ++h)
                bfr[n][h] = *(const bf16x8*)&Bb[(brow0 + n * 16) * BK + ca[h]];
        #pragma unroll
        for (int h = 0; h < NH; ++h)
            #pragma unroll
            for (int m = 0; m < FM; ++m)
                #pragma unroll
                for (int n = 0; n < FN; ++n)
                    acc[m][n] = __builtin_amdgcn_mfma_f32_16x16x32_bf16(
                        af[m][h], bfr[n][h], acc[m][n], 0, 0, 0);
        __syncthreads();
    }

    #pragma unroll
    for (int m = 0; m < FM; ++m) {
        #pragma unroll
        for (int n = 0; n < FN; ++n) {
            #pragma unroll
            for (int r = 0; r < 4; ++r) {
                int grow = bm + wr * WM + m * 16 + g * 4 + r;
                int gcol = bn + wc * WN + n * 16 + lr;
                if (!GUARDN || gcol < Ntot) {
                    float v = acc[m][n][r];
                    int orow = grow;
                    if (ACT == 4) {
                        if (gcol < HDIM) v = fmaxf(v + bias[gcol], 0.f);
                    } else if (ACT == 7) { // Gpre pair-scatter, raw
                        orow = (grow < 1024) ? slot_de(grow) : 2048 + (grow - 1024);
                    }
                    C[(size_t)orow * ldc + gcol] = (__bf16)v;
                }
            }
        }
    }
}

// ---------------------------------------------------------------------------
// stage2: PURE G1 (512 blocks): tmp12 = [relu(x@Wl1+bl1) | x@Wf1_top]
// M=4096 N=256 K=1024, BK=128 dbuf, x reg-staged fp32.
// ---------------------------------------------------------------------------
__global__ __launch_bounds__(256) void stage2_k(
    const float* __restrict__ x, const __bf16* __restrict__ WaT,
    const float* __restrict__ bl1, __bf16* __restrict__ tmp12) {
    __shared__ __bf16 As[8192];
    __shared__ __bf16 Bs[16384];
    const int b = blockIdx.x;
    const int aid = (b & 7) * 64 + (b >> 3);
    const int bn = (aid & 3) * 64, bm = (aid >> 2) * 32;
    gemm_core<32, 64, 128, 2, 4, false, true>(
        x, DDIM, WaT, 1024, 256, bl1, tmp12, 256, 1024, bm, bn, As, Bs,
        threadIdx.x);
}

// ---------------------------------------------------------------------------
// stage3 (512 thr, 72 KB LDS -> 2 blocks/CU):
//   [0,256)   g23: fused G2+G3 (single-buffered B tiles, R19-best schedule)
//   [256,290) Gpre as two 256-thread halves (BK=64, 24 KB/half)
//   [290,422) bias fold (8 waves/block, barrier-free)
// Gpre/bias depend only on pack; their output feeds only mm_pairs -> they
// hide under g23 as second-resident blocks.
// ---------------------------------------------------------------------------
__global__ __launch_bounds__(512) void stage3_k(
    const __bf16* __restrict__ tmp12, const __bf16* __restrict__ Wl2T,
    const __bf16* __restrict__ Wf1bT, const __bf16* __restrict__ WbigT,
    const __bf16* __restrict__ Wf2c,
    const float* __restrict__ bl2, const float* __restrict__ bf1,
    const float* __restrict__ bf2, const float* __restrict__ b1,
    const float* __restrict__ b2, const float* __restrict__ b3,
    __bf16* __restrict__ tmp2, __bf16* __restrict__ WpairT,
    float* __restrict__ bias_pair) {
    __shared__ __bf16 smem[36864]; // 72 KB
    const int b = blockIdx.x;
    const int tid = threadIdx.x;
    if (b < 256) {
        // ---- g23 over 16 tmp2 rows ----
        __bf16* T1 = smem;            // 2048
        __bf16* LS = smem + 2048;     // 2048
        __bf16* B1 = smem + 4096;     // 16384 (single buffer)
        __bf16* B2 = smem + 20480;    // 16384 (single buffer)
        const int lane = tid & 63, w = tid >> 6;
        const int g = lane >> 4, lr = lane & 15;
        const int x7 = lr & 7;
        const int bm = b * 16;

        if (tid < 256) {
            int row = tid >> 4, pos = tid & 15, c = pos ^ (row & 7);
            glds16(&tmp12[(size_t)(bm + row) * 256 + c * 8], &T1[w * 512]);
        }
        auto stageB1 = [&](int kc) {
            #pragma unroll
            for (int i = 0; i < 4; ++i) {
                int D = i * 512 + tid;
                int row = D >> 4, pos = D & 15, c = pos ^ (row & 7);
                glds16(&Wl2T[(size_t)(kc + row) * 128 + c * 8],
                       &B1[(i * 512 + w * 64) * 8]);
            }
        };
        auto stageB2 = [&](int kc) {
            #pragma unroll
            for (int i = 0; i < 4; ++i) {
                int D = i * 512 + tid;
                int row = D >> 4, pos = D & 15, c = pos ^ (row & 7);
                glds16(&Wf1bT[(size_t)row * 1024 + kc + c * 8],
                       &B2[(i * 512 + w * 64) * 8]);
            }
        };

        int ca[4];
        #pragma unroll
        for (int h = 0; h < 4; ++h) ca[h] = ((h * 4 + g) ^ x7) * 8;
        const int col = w * 16 + lr;
        const int brow = col * 128;

        stageB1(0);
        stageB2(0);
        __syncthreads();
        bf16x8 a1[4];
        #pragma unroll
        for (int h = 0; h < 4; ++h) a1[h] = *(const bf16x8*)&T1[lr * 128 + ca[h]];

        f32x4 acc2 = {};
        for (int t = 0; t < 8; ++t) {
            f32x4 acc1 = {};
            #pragma unroll
            for (int h = 0; h < 4; ++h) {
                bf16x8 bf = *(const bf16x8*)&B1[brow + ca[h]];
                acc1 = __builtin_amdgcn_mfma_f32_16x16x32_bf16(a1[h], bf, acc1, 0, 0, 0);
            }
            const float bl = bl2[t * 128 + col];
            const int chunk = col >> 3, cin = col & 7;
            #pragma unroll
            for (int r = 0; r < 4; ++r) {
                float v = acc1[r] + bl;
                float e = __expf(2.f * v);
                v = 1.f - 2.f * __builtin_amdgcn_rcpf(e + 1.f);  // tanh
                int row = g * 4 + r;
                LS[row * 128 + ((chunk ^ (row & 7)) << 3) + cin] = (__bf16)v;
            }
            __syncthreads();                 // sync1: LS visible; B1/B2 reads done
            if (t + 1 < 8) stageB1((t + 1) * 128);
            #pragma unroll
            for (int h = 0; h < 4; ++h) {
                bf16x8 a2 = *(const bf16x8*)&LS[lr * 128 + ca[h]];
                bf16x8 bf = *(const bf16x8*)&B2[brow + ca[h]];
                acc2 = __builtin_amdgcn_mfma_f32_16x16x32_bf16(a2, bf, acc2, 0, 0, 0);
            }
            __syncthreads();                 // sync2: drains B1(t+1); B2/LS free
            if (t + 1 < 8) stageB2((t + 1) * 128);
        }

        const float bfv = bf1[col];
        #pragma unroll
        for (int r = 0; r < 4; ++r) {
            const int row = g * 4 + r;
            float v = acc2[r] + bfv + (float)tmp12[(size_t)(bm + row) * 256 + 128 + col];
            v = fmaxf(v, 0.f);
            tmp2[(size_t)(bm + row) * 128 + col] = (__bf16)v;
        }
    } else if (b < 290) {
        // ---- Gpre: 34 blocks x two 256-thread halves, BK=64 dbuf ----
        const int half = tid >> 8, tidh = tid & 255;
        const int aid = (b - 256) * 2 + half;          // 0..67
        const int bm = (aid >> 1) * 32, bn = (aid & 1) * 64;
        __bf16* Ah = smem + half * 12288;  // 4096 A + 8192 B elems per half
        __bf16* Bh = Ah + 4096;
        gemm_core<32, 64, 64, 2, 7, false, false>(
            WbigT, 1024, Wf2c, 1024, 128, nullptr,
            WpairT, 128, 1024, bm, bn, Ah, Bh, tidh);
    } else {
        // ---- bias fold: 132 blocks x 8 waves ----
        const int n = (b - 290) * 8 + (tid >> 6);
        const int lane = tid & 63;
        const __bf16* wr = WbigT + (size_t)n * 1024 + lane * 16;
        float s = 0.f;
        #pragma unroll
        for (int i = 0; i < 2; ++i) {
            bf16x8 wv = *(const bf16x8*)&wr[i * 8];
            float4 f0 = *(const float4*)&bf2[lane * 16 + i * 8];
            float4 f1 = *(const float4*)&bf2[lane * 16 + i * 8 + 4];
            s += (float)wv[0] * f0.x + (float)wv[1] * f0.y + (float)wv[2] * f0.z +
                 (float)wv[3] * f0.w + (float)wv[4] * f1.x + (float)wv[5] * f1.y +
                 (float)wv[6] * f1.z + (float)wv[7] * f1.w;
        }
        #pragma unroll
        for (int off = 32; off; off >>= 1) s += __shfl_down(s, off);
        if (lane == 0) {
            float base = (n < DDIM) ? b1[n]
                       : (n < DDIM + NDIM) ? b2[n - DDIM] : b3[n - DDIM - NDIM];
            int sl = (n < DDIM) ? slot_de(n) : 2048 + (n - DDIM);
            bias_pair[sl] = base + s;
        }
    }
}

// ---------------------------------------------------------------------------
// mm_pairs: [xt|de] pair GEMM + in-kernel BC (Bm/Cm/cb) + final epilogue.
// M=4096 N=2048 K=128. BM=128 BN=64, 1024 blocks, LDS 48 KB. (unchanged)
// ---------------------------------------------------------------------------
__global__ __launch_bounds__(256) void mm_pairs(
    const __bf16* __restrict__ tmp2, const __bf16* __restrict__ WpairT,
    const float* __restrict__ bias_pair,
    const float* __restrict__ Amat, const float* __restrict__ h0,
    const unsigned* __restrict__ h0mask,
    float* __restrict__ out, float* __restrict__ last_h) {
    constexpr int ASZ = 128 * 64, BSZ = 64 * 64;
    __shared__ __bf16 As[2 * ASZ];
    __shared__ __bf16 Bs[2 * BSZ];
    const int NB = gridDim.x; // 1024
    const int aid = (blockIdx.x & 7) * (NB >> 3) + (blockIdx.x >> 3);
    const int bn = (aid & 31) * 64, bm = (aid >> 5) * 128;
    const int tid = threadIdx.x;
    const int lane = tid & 63, w = tid >> 6;
    const int wr = w >> 1, wc = w & 1;
    const int g = lane >> 4, lr = lane & 15;

    auto stage = [&](int buf, int k0) {
        #pragma unroll
        for (int i = 0; i < 4; ++i) {
            int D = i * 256 + tid;
            int row = D >> 3, pos = D & 7, c = pos ^ (row & 7);
            glds16(&tmp2[(size_t)(bm + row) * 128 + k0 + c * 8],
                   &As[buf * ASZ + (i * 256 + w * 64) * 8]);
        }
        #pragma unroll
        for (int i = 0; i < 2; ++i) {
            int D = i * 256 + tid;
            int row = D >> 3, pos = D & 7, c = pos ^ (row & 7);
            glds16(&WpairT[(size_t)(bn + row) * 128 + k0 + c * 8],
                   &Bs[buf * BSZ + (i * 256 + w * 64) * 8]);
        }
    };

    f32x4 acc[4][2] = {};
    const int x7 = lr & 7;
    const int ca[2] = {(g ^ x7) * 8, ((4 + g) ^ x7) * 8};
    const int arow0 = wr * 64 + lr, brow0 = wc * 32 + lr;
    stage(0, 0);
    __syncthreads();
    #pragma unroll
    for (int t = 0; t < 2; ++t) {
        if (t == 0) stage(1, 64);
        const __bf16* Ab = &As[t * ASZ];
        const __bf16* Bb = &Bs[t * BSZ];
        bf16x8 af[4][2], bfr[2][2];
        #pragma unroll
        for (int m = 0; m < 4; ++m)
            #pragma unroll
            for (int h = 0; h < 2; ++h)
                af[m][h] = *(const bf16x8*)&Ab[(arow0 + m * 16) * 64 + ca[h]];
        #pragma unroll
        for (int n = 0; n < 2; ++n)
            #pragma unroll
            for (int h = 0; h < 2; ++h)
                bfr[n][h] = *(const bf16x8*)&Bb[(brow0 + n * 16) * 64 + ca[h]];
        #pragma unroll
        for (int h = 0; h < 2; ++h)
            #pragma unroll
            for (int m = 0; m < 4; ++m)
                #pragma unroll
                for (int n = 0; n < 2; ++n)
                    acc[m][n] = __builtin_amdgcn_mfma_f32_16x16x32_bf16(
                        af[m][h], bfr[n][h], acc[m][n], 0, 0, 0);
        __syncthreads();
    }

    // in-kernel BC
    {
        int row = tid >> 3, pos = tid & 7, c = pos ^ (row & 7);
        #pragma unroll
        for (int t2 = 0; t2 < 2; ++t2)
            glds16(&WpairT[(size_t)(2048 + row) * 128 + t2 * 64 + c * 8],
                   &Bs[t2 * 2048 + w * 512]);
    }
    __syncthreads();
    f32x4 accB[2] = {}, accC[2] = {};
    #pragma unroll
    for (int t2 = 0; t2 < 2; ++t2) {
        const __bf16* Ab = &As[t2 * ASZ];
        #pragma unroll
        for (int h = 0; h < 2; ++h) {
            bf16x8 bB = *(const bf16x8*)&Bs[t2 * 2048 + lr * 64 + ca[h]];
            bf16x8 bC = *(const bf16x8*)&Bs[t2 * 2048 + (16 + lr) * 64 + ca[h]];
            #pragma unroll
            for (int m2 = 0; m2 < 2; ++m2) {
                bf16x8 a2 = *(const bf16x8*)&Ab[(w * 32 + m2 * 16 + lr) * 64 + ca[h]];
                accB[m2] = __builtin_amdgcn_mfma_f32_16x16x32_bf16(a2, bB, accB[m2], 0, 0, 0);
                accC[m2] = __builtin_amdgcn_mfma_f32_16x16x32_bf16(a2, bC, accC[m2], 0, 0, 0);
            }
        }
    }
    __syncthreads();
    float* sCB = (float*)As;
    __bf16* sBC = &Bs[BSZ];
    const float bB_ = bias_pair[2048 + lr], bC_ = bias_pair[2064 + lr];
    #pragma unroll
    for (int m2 = 0; m2 < 2; ++m2) {
        #pragma unroll
        for (int r = 0; r < 4; ++r) {
            int lrow = w * 32 + m2 * 16 + g * 4 + r;
            float vB = accB[m2][r] + bB_;
            float vC = accC[m2][r] + bC_;
            sBC[lrow * 32 + lr] = (__bf16)vB;
            sBC[lrow * 32 + 16 + lr] = (__bf16)vC;
            float p = vB * vC;
            #pragma unroll
            for (int m3 = 1; m3 < 16; m3 <<= 1) p += __shfl_xor(p, m3);
            if (lr == 0) sCB[lrow] = p;
        }
    }
    __syncthreads();

    const int d = ((bn + wc * 32) >> 1) + lr;
    const float bx_ = bias_pair[bn + wc * 32 + lr];
    const float bd_ = bias_pair[bn + wc * 32 + 16 + lr];
    const bool msk = (h0mask[d >> 5] >> (d & 31)) & 1u;
    #pragma unroll
    for (int m = 0; m < 4; ++m) {
        #pragma unroll
        for (int r = 0; r < 4; ++r) {
            const int lrow = wr * 64 + m * 16 + g * 4 + r;
            const int row = bm + lrow;
            const float xt = acc[m][0][r] + bx_;
            const float dr = acc[m][1][r] + bd_;
            const float e = __expf(-fabsf(dr));
            const float de = fmaxf(dr, 0.f) + __logf(1.f + e);
            const float xd = xt * de;
            float res = xd * sCB[lrow];
            const bool is_last = (row & (LSEQ - 1)) == (LSEQ - 1);
            if (msk) {
                float s = 0.f;
                #pragma unroll
                for (int n = 0; n < NDIM; ++n) {
                    float z = de * Amat[d * NDIM + n];
                    float c2 = (z > 0.f) ? z : __expf(z) - 1.f;
                    float da = __expf(-c2);
                    float h0v = h0[d * NDIM + n];
                    s += (float)sBC[lrow * 32 + 16 + n] * da * h0v;
                    if (is_last)
                        last_h[(((size_t)(row >> 11)) * DDIM + d) * NDIM + n] =
                            da * h0v + xd * (float)sBC[lrow * 32 + n];
                }
                res += s;
            } else if (is_last) {
                #pragma unroll
                for (int n = 0; n < NDIM; ++n)
                    last_h[(((size_t)(row >> 11)) * DDIM + d) * NDIM + n] =
                        xd * (float)sBC[lrow * 32 + n];
            }
            out[(size_t)row * DDIM + d] = res;
        }
    }
}

extern "C" void kernel_launch(void* const* d_in, const int* in_sizes, int n_in,
                              void* d_out, int out_size, void* d_ws, size_t ws_size,
                              hipStream_t stream) {
    const float* x   = (const float*)d_in[0];
    const float* W1  = (const float*)d_in[1];
    const float* b1  = (const float*)d_in[2];
    const float* W2  = (const float*)d_in[3];
    const float* b2  = (const float*)d_in[4];
    const float* W3  = (const float*)d_in[5];
    const float* b3  = (const float*)d_in[6];
    const float* Wl1 = (const float*)d_in[7];
    const float* bl1 = (const float*)d_in[8];
    const float* Wl2 = (const float*)d_in[9];
    const float* bl2 = (const float*)d_in[10];
    const float* Wf1 = (const float*)d_in[11];
    const float* bf1 = (const float*)d_in[12];
    const float* Wf2 = (const float*)d_in[13];
    const float* bf2 = (const float*)d_in[14];
    const float* h0  = (const float*)d_in[15];
    const float* Amat= (const float*)d_in[16];

    float* out    = (float*)d_out;
    float* last_h = (float*)d_out + (size_t)MROWS * DDIM;

    __bf16* wsb = (__bf16*)d_ws;
    size_t o = 0;
    auto alloc = [&](size_t n) { __bf16* p = wsb + o; o += n; return p; };
    __bf16* WaT    = alloc(256 * 1024);             // [Wl1 | Wf1_top]^T
    __bf16* Wf1bT  = alloc(128 * 1024);
    __bf16* Wl2T   = alloc(1024 * 128);
    __bf16* WbigT  = alloc((size_t)NPAD * 1024);    // [W1 | W2 | W3 | pad]^T
    __bf16* WpairT = alloc(2112 * 128);             // pairs 0..2047, BC 2048..2079
    __bf16* Wf2c   = alloc(128 * 1024);             // Wf2 bf16 row-major
    __bf16* tmp12  = alloc((size_t)MROWS * 256);    // [relu(x@Wl1+bl1) | x@Wf1_top]
    __bf16* tmp2   = alloc((size_t)MROWS * HDIM);
    float*  bias_pair = (float*)(wsb + o); o += 2 * 2112;
    unsigned* h0mask = (unsigned*)(wsb + o);

    // 1. pack (flat 1797 blocks)
    pack_all<<<dim3(1797), 256, 0, stream>>>(W1, W2, W3, Wl1, Wl2, Wf1, Wf2,
                                             bf2, h0,
                                             WbigT, WaT, Wf1bT, Wl2T, WpairT,
                                             Wf2c, bias_pair, h0mask);
    // 2. stage2: pure G1 (512 blocks)
    stage2_k<<<dim3(512), 256, 0, stream>>>(x, WaT, bl1, tmp12);
    // 3. stage3: g23 (256) || Gpre (34 dual-half) || bias fold (132)
    stage3_k<<<dim3(422), 512, 0, stream>>>(tmp12, Wl2T, Wf1bT, WbigT, Wf2c,
                                            bl2, bf1, bf2, b1, b2, b3,
                                            tmp2, WpairT, bias_pair);
    // 4. mm_pairs -> out, last_h
    mm_pairs<<<dim3(32 * 32), 256, 0, stream>>>(tmp2, WpairT, bias_pair,
                                                Amat, h0, h0mask, out, last_h);
}